// Round 1
// baseline (2509.978 us; speedup 1.0000x reference)
//
#include <hip/hip_runtime.h>
#include <math.h>

#define B_  16
#define L_  1024
#define INPUT_ 40
#define DM  256
#define DS  16
#define NL  4
#define DC  4
#define DI  512
#define DTR 16
#define BL  (B_ * L_)   // 16384

// ---------------------------------------------------------------------------
// Generic tiled f32 GEMM:  C[m][n] = op( sum_k A[m*lda+k] * W[n*ldw+k] + bias[n] )
// optional residual add (Cin) and softplus activation.
// BM=BN=64, BK=16, 256 threads, 4x4 per thread.
// ---------------------------------------------------------------------------
#define GBM 64
#define GBN 64
#define GBK 16

__global__ __launch_bounds__(256) void gemm_nt(
    const float* __restrict__ A, int lda,
    const float* __restrict__ W, int ldw,
    const float* __restrict__ bias,
    const float* __restrict__ Cin,   // residual (may alias C) or nullptr
    float* __restrict__ C, int ldc,
    int N, int K, int act)           // act: 0 none, 1 softplus
{
    __shared__ float As[GBK][GBM];
    __shared__ float Ws[GBK][GBN];

    const int tid = threadIdx.x;
    const int m0 = blockIdx.x * GBM;
    const int n0 = blockIdx.y * GBN;
    const int tx = tid & 15;         // 0..15 (n)
    const int ty = tid >> 4;         // 0..15 (m)
    const int r  = tid >> 2;         // 0..63 load row
    const int kq = (tid & 3) * 4;    // 0,4,8,12 load k-quad

    float acc[4][4];
#pragma unroll
    for (int i = 0; i < 4; ++i)
#pragma unroll
        for (int j = 0; j < 4; ++j) acc[i][j] = 0.f;

    for (int k0 = 0; k0 < K; k0 += GBK) {
        // ---- load A tile (transposed into LDS) ----
        {
            float4 v = make_float4(0.f, 0.f, 0.f, 0.f);
            const int row = m0 + r;
            if (k0 + kq + 3 < K) {
                v = *reinterpret_cast<const float4*>(&A[(size_t)row * lda + k0 + kq]);
            } else {
                float t0 = (k0+kq+0 < K) ? A[(size_t)row*lda + k0+kq+0] : 0.f;
                float t1 = (k0+kq+1 < K) ? A[(size_t)row*lda + k0+kq+1] : 0.f;
                float t2 = (k0+kq+2 < K) ? A[(size_t)row*lda + k0+kq+2] : 0.f;
                float t3 = (k0+kq+3 < K) ? A[(size_t)row*lda + k0+kq+3] : 0.f;
                v = make_float4(t0, t1, t2, t3);
            }
            As[kq+0][r] = v.x; As[kq+1][r] = v.y; As[kq+2][r] = v.z; As[kq+3][r] = v.w;
        }
        // ---- load W tile (transposed into LDS) ----
        {
            float4 v = make_float4(0.f, 0.f, 0.f, 0.f);
            const int row = n0 + r;
            if (row < N) {
                if (k0 + kq + 3 < K) {
                    v = *reinterpret_cast<const float4*>(&W[(size_t)row * ldw + k0 + kq]);
                } else {
                    float t0 = (k0+kq+0 < K) ? W[(size_t)row*ldw + k0+kq+0] : 0.f;
                    float t1 = (k0+kq+1 < K) ? W[(size_t)row*ldw + k0+kq+1] : 0.f;
                    float t2 = (k0+kq+2 < K) ? W[(size_t)row*ldw + k0+kq+2] : 0.f;
                    float t3 = (k0+kq+3 < K) ? W[(size_t)row*ldw + k0+kq+3] : 0.f;
                    v = make_float4(t0, t1, t2, t3);
                }
            }
            Ws[kq+0][r] = v.x; Ws[kq+1][r] = v.y; Ws[kq+2][r] = v.z; Ws[kq+3][r] = v.w;
        }
        __syncthreads();

#pragma unroll
        for (int k = 0; k < GBK; ++k) {
            const float4 a = *reinterpret_cast<const float4*>(&As[k][ty * 4]);
            const float4 b = *reinterpret_cast<const float4*>(&Ws[k][tx * 4]);
            acc[0][0] = fmaf(a.x, b.x, acc[0][0]);
            acc[0][1] = fmaf(a.x, b.y, acc[0][1]);
            acc[0][2] = fmaf(a.x, b.z, acc[0][2]);
            acc[0][3] = fmaf(a.x, b.w, acc[0][3]);
            acc[1][0] = fmaf(a.y, b.x, acc[1][0]);
            acc[1][1] = fmaf(a.y, b.y, acc[1][1]);
            acc[1][2] = fmaf(a.y, b.z, acc[1][2]);
            acc[1][3] = fmaf(a.y, b.w, acc[1][3]);
            acc[2][0] = fmaf(a.z, b.x, acc[2][0]);
            acc[2][1] = fmaf(a.z, b.y, acc[2][1]);
            acc[2][2] = fmaf(a.z, b.z, acc[2][2]);
            acc[2][3] = fmaf(a.z, b.w, acc[2][3]);
            acc[3][0] = fmaf(a.w, b.x, acc[3][0]);
            acc[3][1] = fmaf(a.w, b.y, acc[3][1]);
            acc[3][2] = fmaf(a.w, b.z, acc[3][2]);
            acc[3][3] = fmaf(a.w, b.w, acc[3][3]);
        }
        __syncthreads();
    }

#pragma unroll
    for (int i = 0; i < 4; ++i) {
        const int row = m0 + ty * 4 + i;
#pragma unroll
        for (int j = 0; j < 4; ++j) {
            const int col = n0 + tx * 4 + j;
            if (col < N) {
                float v = acc[i][j];
                if (bias) v += bias[col];
                if (act == 1) v = (v > 20.f) ? v : log1pf(expf(v));  // softplus
                if (Cin) v += Cin[(size_t)row * ldc + col];
                C[(size_t)row * ldc + col] = v;
            }
        }
    }
}

// ---------------------------------------------------------------------------
// LayerNorm: one wave (64 threads) per row of 256.
// ---------------------------------------------------------------------------
__global__ __launch_bounds__(64) void ln_kernel(
    const float* __restrict__ h, const float* __restrict__ g,
    const float* __restrict__ bb, float* __restrict__ out)
{
    const int row = blockIdx.x;
    const int lane = threadIdx.x;
    const float4 v = *reinterpret_cast<const float4*>(&h[(size_t)row * DM + lane * 4]);
    float s  = v.x + v.y + v.z + v.w;
    float s2 = v.x*v.x + v.y*v.y + v.z*v.z + v.w*v.w;
#pragma unroll
    for (int m = 1; m < 64; m <<= 1) {
        s  += __shfl_xor(s, m);
        s2 += __shfl_xor(s2, m);
    }
    const float mu  = s * (1.f / DM);
    const float var = s2 * (1.f / DM) - mu * mu;
    const float rs  = rsqrtf(var + 1e-5f);
    const float4 gv = *reinterpret_cast<const float4*>(&g[lane * 4]);
    const float4 bv = *reinterpret_cast<const float4*>(&bb[lane * 4]);
    float4 o;
    o.x = (v.x - mu) * rs * gv.x + bv.x;
    o.y = (v.y - mu) * rs * gv.y + bv.y;
    o.z = (v.z - mu) * rs * gv.z + bv.z;
    o.w = (v.w - mu) * rs * gv.w + bv.w;
    *reinterpret_cast<float4*>(&out[(size_t)row * DM + lane * 4]) = o;
}

// ---------------------------------------------------------------------------
// Causal depthwise conv (k=4, left pad 3) + bias + SiLU. xi = xz[:, :512].
// ---------------------------------------------------------------------------
__global__ __launch_bounds__(256) void conv_silu(
    const float* __restrict__ xz, const float* __restrict__ cw,
    const float* __restrict__ cb, float* __restrict__ xc)
{
    const int idx = blockIdx.x * 256 + threadIdx.x;   // BL*512 total
    const int d   = idx & (DI - 1);
    const int row = idx >> 9;                          // b*L + t
    const int t   = row & (L_ - 1);
    const float w0 = cw[d*4+0], w1 = cw[d*4+1], w2 = cw[d*4+2], w3 = cw[d*4+3];
    const float* base = xz + (size_t)row * (2*DI) + d;
    float acc = cb[d] + w3 * base[0];
    if (t >= 1) acc = fmaf(w2, base[-(2*DI)],   acc);
    if (t >= 2) acc = fmaf(w1, base[-2*(2*DI)], acc);
    if (t >= 3) acc = fmaf(w0, base[-3*(2*DI)], acc);
    xc[idx] = acc / (1.f + __expf(-acc));              // silu
}

// ---------------------------------------------------------------------------
// Selective scan. Thread = (b, d, n). Block = 256 threads = 16 d x 16 n.
// Writes ycomb = (y + xc*Dsk) * silu(z).
// ---------------------------------------------------------------------------
#define TCH 64
__global__ __launch_bounds__(256) void scan_kernel(
    const float* __restrict__ dt,    // [BL][512]
    const float* __restrict__ xc,    // [BL][512]
    const float* __restrict__ xdbl,  // [BL][48]  (B at +16, C at +32)
    const float* __restrict__ xz,    // [BL][1024] (z at +512)
    const float* __restrict__ Alog,  // [512][16]
    const float* __restrict__ Dsk,   // [512]
    float* __restrict__ yout)        // [BL][512]
{
    __shared__ float sdt[TCH][16], sxc[TCH][16], sB[TCH][16], sC[TCH][16], sz[TCH][16];
    const int b   = blockIdx.x;
    const int d0  = blockIdx.y * 16;
    const int tid = threadIdx.x;
    const int dg  = tid >> 4;
    const int n   = tid & 15;
    const int d   = d0 + dg;

    const float Adn  = -__expf(Alog[d * DS + n]);
    const float dskd = Dsk[d];
    float h = 0.f;

    for (int tc = 0; tc < L_; tc += TCH) {
#pragma unroll
        for (int q = 0; q < 4; ++q) {
            const int idx  = q * 256 + tid;
            const int toff = idx >> 4;
            const int col  = idx & 15;
            const size_t row = (size_t)b * L_ + tc + toff;
            sdt[toff][col] = dt[row * DI + d0 + col];
            sxc[toff][col] = xc[row * DI + d0 + col];
            sB [toff][col] = xdbl[row * 48 + DTR + col];
            sC [toff][col] = xdbl[row * 48 + DTR + DS + col];
            sz [toff][col] = xz[row * (2*DI) + DI + d0 + col];
        }
        __syncthreads();

        for (int tt = 0; tt < TCH; ++tt) {
            const float dtv = sdt[tt][dg];
            const float xv  = sxc[tt][dg];
            const float bv  = sB[tt][n];
            const float cv  = sC[tt][n];
            const float a   = __expf(dtv * Adn);
            h = fmaf(h, a, dtv * xv * bv);
            float y = h * cv;
            y += __shfl_xor(y, 1, 16);
            y += __shfl_xor(y, 2, 16);
            y += __shfl_xor(y, 4, 16);
            y += __shfl_xor(y, 8, 16);
            if (n == 0) {
                const float zv = sz[tt][dg];
                const float sz_ = zv / (1.f + __expf(-zv));
                yout[((size_t)b * L_ + tc + tt) * DI + d] = (y + xv * dskd) * sz_;
            }
        }
        __syncthreads();
    }
}

// ---------------------------------------------------------------------------
// mask mean over the INPUT dim
// ---------------------------------------------------------------------------
__global__ __launch_bounds__(256) void maskmean_kernel(
    const float* __restrict__ mask, float* __restrict__ m)
{
    const int row = blockIdx.x * 256 + threadIdx.x;    // BL
    const float* p = mask + (size_t)row * INPUT_;
    float s = 0.f;
#pragma unroll
    for (int k = 0; k < INPUT_; ++k) s += p[k];
    m[row] = s * (1.f / INPUT_);
}

// ---------------------------------------------------------------------------
// masked mean pool over L
// ---------------------------------------------------------------------------
__global__ __launch_bounds__(256) void pool_kernel(
    const float* __restrict__ h, const float* __restrict__ m,
    float* __restrict__ pooled)
{
    const int b = blockIdx.x;
    const int c = threadIdx.x;
    float acc = 0.f, ms = 0.f;
    for (int l = 0; l < L_; ++l) {
        const float mv = m[b * L_ + l];
        acc = fmaf(h[((size_t)b * L_ + l) * DM + c], mv, acc);
        ms += mv;
    }
    pooled[b * DM + c] = acc / (ms + 1e-8f);
}

// ---------------------------------------------------------------------------
// head: fc1 + exact GELU + fc2
// ---------------------------------------------------------------------------
__global__ __launch_bounds__(128) void head_kernel(
    const float* __restrict__ pooled,
    const float* __restrict__ fc1w, const float* __restrict__ fc1b,
    const float* __restrict__ fc2w, const float* __restrict__ fc2b,
    float* __restrict__ out)
{
    __shared__ float sp[DM];
    __shared__ float sh[128];
    const int b = blockIdx.x;
    const int j = threadIdx.x;
    sp[j]       = pooled[b * DM + j];
    sp[j + 128] = pooled[b * DM + j + 128];
    __syncthreads();
    float acc = fc1b[j];
    for (int k = 0; k < DM; ++k) acc = fmaf(sp[k], fc1w[j * DM + k], acc);
    const float g = 0.5f * acc * (1.f + erff(acc * 0.70710678118654752f));
    sh[j] = g * fc2w[j];
    __syncthreads();
    for (int s = 64; s > 0; s >>= 1) {
        if (j < s) sh[j] += sh[j + s];
        __syncthreads();
    }
    if (j == 0) out[b] = sh[0] + fc2b[0];
}

// ---------------------------------------------------------------------------
extern "C" void kernel_launch(void* const* d_in, const int* in_sizes, int n_in,
                              void* d_out, int out_size, void* d_ws, size_t ws_size,
                              hipStream_t stream)
{
    const float* x       = (const float*)d_in[0];
    const float* mask    = (const float*)d_in[1];
    const float* ipw     = (const float*)d_in[2];
    const float* ipb     = (const float*)d_in[3];
    const float* in_w    = (const float*)d_in[4];
    const float* conv_w  = (const float*)d_in[5];
    const float* conv_b  = (const float*)d_in[6];
    const float* xpw     = (const float*)d_in[7];
    const float* dtw     = (const float*)d_in[8];
    const float* dtb     = (const float*)d_in[9];
    const float* A_log   = (const float*)d_in[10];
    const float* D_skip  = (const float*)d_in[11];
    const float* out_w   = (const float*)d_in[12];
    const float* ln_g    = (const float*)d_in[13];
    const float* ln_b    = (const float*)d_in[14];
    const float* fc1w    = (const float*)d_in[15];
    const float* fc1b    = (const float*)d_in[16];
    const float* fc2w    = (const float*)d_in[17];
    const float* fc2b    = (const float*)d_in[18];
    float* outp = (float*)d_out;

    // workspace carve-up (bytes, 256-aligned)
    char* ws = (char*)d_ws;
    size_t off = 0;
    auto alloc = [&](size_t nfloats) {
        float* p = (float*)(ws + off);
        off += ((nfloats * 4 + 255) / 256) * 256;
        return p;
    };
    float* hbuf   = alloc((size_t)BL * DM);        // residual stream
    float* xln    = alloc((size_t)BL * DM);
    float* xzbuf  = alloc((size_t)BL * 2 * DI);
    float* xcbuf  = alloc((size_t)BL * DI);
    float* xdbl   = alloc((size_t)BL * 48);
    float* dtbuf  = alloc((size_t)BL * DI);
    float* ycomb  = alloc((size_t)BL * DI);
    float* mbuf   = alloc((size_t)BL);
    float* pooled = alloc((size_t)B_ * DM);
    (void)ws_size; (void)n_in; (void)in_sizes; (void)out_size;

    const dim3 blk(256);

    // input projection: h = x @ ipw.T + ipb   (M=BL, N=256, K=40)
    gemm_nt<<<dim3(BL/GBM, DM/GBN), blk, 0, stream>>>(
        x, INPUT_, ipw, INPUT_, ipb, nullptr, hbuf, DM, DM, INPUT_, 0);

    for (int i = 0; i < NL; ++i) {
        const float* in_wi  = in_w   + (size_t)i * 2 * DI * DM;
        const float* cwi    = conv_w + (size_t)i * DI * DC;
        const float* cbi    = conv_b + (size_t)i * DI;
        const float* xpwi   = xpw    + (size_t)i * 48 * DI;
        const float* dtwi   = dtw    + (size_t)i * DI * DTR;
        const float* dtbi   = dtb    + (size_t)i * DI;
        const float* Alogi  = A_log  + (size_t)i * DI * DS;
        const float* Dski   = D_skip + (size_t)i * DI;
        const float* owi    = out_w  + (size_t)i * DM * DI;
        const float* lngi   = ln_g   + (size_t)i * DM;
        const float* lnbi   = ln_b   + (size_t)i * DM;

        // layernorm
        ln_kernel<<<BL, 64, 0, stream>>>(hbuf, lngi, lnbi, xln);

        // xz = xln @ in_w.T  (N=1024, K=256)
        gemm_nt<<<dim3(BL/GBM, (2*DI)/GBN), blk, 0, stream>>>(
            xln, DM, in_wi, DM, nullptr, nullptr, xzbuf, 2*DI, 2*DI, DM, 0);

        // conv + silu -> xc
        conv_silu<<<(BL * DI) / 256, blk, 0, stream>>>(xzbuf, cwi, cbi, xcbuf);

        // x_dbl = xc @ xpw.T  (N=48, K=512)
        gemm_nt<<<dim3(BL/GBM, 1), blk, 0, stream>>>(
            xcbuf, DI, xpwi, DI, nullptr, nullptr, xdbl, 48, 48, DI, 0);

        // dt = softplus(x_dbl[:, :16] @ dtw.T + dtb)  (N=512, K=16)
        gemm_nt<<<dim3(BL/GBM, DI/GBN), blk, 0, stream>>>(
            xdbl, 48, dtwi, DTR, dtbi, nullptr, dtbuf, DI, DI, DTR, 1);

        // selective scan -> ycomb = (y + xc*D) * silu(z)
        scan_kernel<<<dim3(B_, DI/16), blk, 0, stream>>>(
            dtbuf, xcbuf, xdbl, xzbuf, Alogi, Dski, ycomb);

        // h += ycomb @ ow.T  (N=256, K=512)
        gemm_nt<<<dim3(BL/GBM, DM/GBN), blk, 0, stream>>>(
            ycomb, DI, owi, DI, nullptr, hbuf, hbuf, DM, DM, DI, 0);
    }

    maskmean_kernel<<<BL / 256, blk, 0, stream>>>(mask, mbuf);
    pool_kernel<<<B_, blk, 0, stream>>>(hbuf, mbuf, pooled);
    head_kernel<<<B_, dim3(128), 0, stream>>>(pooled, fc1w, fc1b, fc2w, fc2b, outp);
}

// Round 2
// 2387.641 us; speedup vs baseline: 1.0512x; 1.0512x over previous
//
#include <hip/hip_runtime.h>
#include <math.h>

#define B_  16
#define L_  1024
#define INPUT_ 40
#define DM  256
#define DS  16
#define NL  4
#define DC  4
#define DI  512
#define DTR 16
#define BL  (B_ * L_)   // 16384
#define NC  16          // scan chunks
#define CH  64          // timesteps per chunk (NC*CH == L_)
#define PCH 16          // pool chunks over L

// ---------------------------------------------------------------------------
// Tiled f32 GEMM:  C[m][n] = op( sum_k A[m*lda+k] * W[n*ldw+k] + bias[n] )
// BM=BN=128, BK=16, 256 threads, 8x8 per thread. M must be multiple of 128.
// ---------------------------------------------------------------------------
#define GBM 128
#define GBN 128
#define GBK 16

__global__ __launch_bounds__(256) void gemm_nt(
    const float* __restrict__ A, int lda,
    const float* __restrict__ W, int ldw,
    const float* __restrict__ bias,
    const float* __restrict__ Cin,   // residual (may alias C) or nullptr
    float* __restrict__ C, int ldc,
    int N, int K, int act)           // act: 0 none, 1 softplus
{
    __shared__ float As[GBK][GBM];
    __shared__ float Ws[GBK][GBN];

    const int tid = threadIdx.x;
    const int m0 = blockIdx.x * GBM;
    const int n0 = blockIdx.y * GBN;
    const int tx = tid & 15;         // 0..15 (n)
    const int ty = tid >> 4;         // 0..15 (m)
    const int r  = tid >> 1;         // 0..127 load row
    const int kq = (tid & 1) * 8;    // 0 or 8: k-octet

    float acc[8][8];
#pragma unroll
    for (int i = 0; i < 8; ++i)
#pragma unroll
        for (int j = 0; j < 8; ++j) acc[i][j] = 0.f;

    for (int k0 = 0; k0 < K; k0 += GBK) {
        // ---- stage A tile (transposed into LDS) ----
        {
            const int row = m0 + r;
            if (k0 + kq + 7 < K) {
                const float4 v0 = *reinterpret_cast<const float4*>(&A[(size_t)row * lda + k0 + kq]);
                const float4 v1 = *reinterpret_cast<const float4*>(&A[(size_t)row * lda + k0 + kq + 4]);
                As[kq+0][r] = v0.x; As[kq+1][r] = v0.y; As[kq+2][r] = v0.z; As[kq+3][r] = v0.w;
                As[kq+4][r] = v1.x; As[kq+5][r] = v1.y; As[kq+6][r] = v1.z; As[kq+7][r] = v1.w;
            } else {
#pragma unroll
                for (int i = 0; i < 8; ++i)
                    As[kq+i][r] = (k0 + kq + i < K) ? A[(size_t)row * lda + k0 + kq + i] : 0.f;
            }
        }
        // ---- stage W tile (transposed into LDS) ----
        {
            const int row = n0 + r;
            if (row < N && k0 + kq + 7 < K) {
                const float4 v0 = *reinterpret_cast<const float4*>(&W[(size_t)row * ldw + k0 + kq]);
                const float4 v1 = *reinterpret_cast<const float4*>(&W[(size_t)row * ldw + k0 + kq + 4]);
                Ws[kq+0][r] = v0.x; Ws[kq+1][r] = v0.y; Ws[kq+2][r] = v0.z; Ws[kq+3][r] = v0.w;
                Ws[kq+4][r] = v1.x; Ws[kq+5][r] = v1.y; Ws[kq+6][r] = v1.z; Ws[kq+7][r] = v1.w;
            } else {
#pragma unroll
                for (int i = 0; i < 8; ++i)
                    Ws[kq+i][r] = (row < N && k0 + kq + i < K) ? W[(size_t)row * ldw + k0 + kq + i] : 0.f;
            }
        }
        __syncthreads();

#pragma unroll
        for (int k = 0; k < GBK; ++k) {
            const float4 a0 = *reinterpret_cast<const float4*>(&As[k][ty * 8]);
            const float4 a1 = *reinterpret_cast<const float4*>(&As[k][ty * 8 + 4]);
            const float4 b0 = *reinterpret_cast<const float4*>(&Ws[k][tx * 8]);
            const float4 b1 = *reinterpret_cast<const float4*>(&Ws[k][tx * 8 + 4]);
            const float av[8] = {a0.x, a0.y, a0.z, a0.w, a1.x, a1.y, a1.z, a1.w};
            const float bv[8] = {b0.x, b0.y, b0.z, b0.w, b1.x, b1.y, b1.z, b1.w};
#pragma unroll
            for (int i = 0; i < 8; ++i)
#pragma unroll
                for (int j = 0; j < 8; ++j)
                    acc[i][j] = fmaf(av[i], bv[j], acc[i][j]);
        }
        __syncthreads();
    }

#pragma unroll
    for (int i = 0; i < 8; ++i) {
        const int row = m0 + ty * 8 + i;
#pragma unroll
        for (int j = 0; j < 8; ++j) {
            const int col = n0 + tx * 8 + j;
            if (col < N) {
                float v = acc[i][j];
                if (bias) v += bias[col];
                if (act == 1) v = (v > 20.f) ? v : log1pf(expf(v));  // softplus
                if (Cin) v += Cin[(size_t)row * ldc + col];
                C[(size_t)row * ldc + col] = v;
            }
        }
    }
}

// ---------------------------------------------------------------------------
// LayerNorm: one wave (64 threads) per row of 256.
// ---------------------------------------------------------------------------
__global__ __launch_bounds__(64) void ln_kernel(
    const float* __restrict__ h, const float* __restrict__ g,
    const float* __restrict__ bb, float* __restrict__ out)
{
    const int row = blockIdx.x;
    const int lane = threadIdx.x;
    const float4 v = *reinterpret_cast<const float4*>(&h[(size_t)row * DM + lane * 4]);
    float s  = v.x + v.y + v.z + v.w;
    float s2 = v.x*v.x + v.y*v.y + v.z*v.z + v.w*v.w;
#pragma unroll
    for (int m = 1; m < 64; m <<= 1) {
        s  += __shfl_xor(s, m);
        s2 += __shfl_xor(s2, m);
    }
    const float mu  = s * (1.f / DM);
    const float var = s2 * (1.f / DM) - mu * mu;
    const float rs  = rsqrtf(var + 1e-5f);
    const float4 gv = *reinterpret_cast<const float4*>(&g[lane * 4]);
    const float4 bv = *reinterpret_cast<const float4*>(&bb[lane * 4]);
    float4 o;
    o.x = (v.x - mu) * rs * gv.x + bv.x;
    o.y = (v.y - mu) * rs * gv.y + bv.y;
    o.z = (v.z - mu) * rs * gv.z + bv.z;
    o.w = (v.w - mu) * rs * gv.w + bv.w;
    *reinterpret_cast<float4*>(&out[(size_t)row * DM + lane * 4]) = o;
}

// ---------------------------------------------------------------------------
// Causal depthwise conv (k=4, left pad 3) + bias + SiLU. xi = xz[:, :512].
// ---------------------------------------------------------------------------
__global__ __launch_bounds__(256) void conv_silu(
    const float* __restrict__ xz, const float* __restrict__ cw,
    const float* __restrict__ cb, float* __restrict__ xc)
{
    const int idx = blockIdx.x * 256 + threadIdx.x;   // BL*512 total
    const int d   = idx & (DI - 1);
    const int row = idx >> 9;                          // b*L + t
    const int t   = row & (L_ - 1);
    const float w0 = cw[d*4+0], w1 = cw[d*4+1], w2 = cw[d*4+2], w3 = cw[d*4+3];
    const float* base = xz + (size_t)row * (2*DI) + d;
    float acc = cb[d] + w3 * base[0];
    if (t >= 1) acc = fmaf(w2, base[-(2*DI)],   acc);
    if (t >= 2) acc = fmaf(w1, base[-2*(2*DI)], acc);
    if (t >= 3) acc = fmaf(w0, base[-3*(2*DI)], acc);
    xc[idx] = acc / (1.f + __expf(-acc));              // silu
}

// ---------------------------------------------------------------------------
// Selective scan, chunk-parallel (linear recurrence h' = a*h + u).
// Pass 1: per chunk compute (P, q) with h_end = P*h_start + q.
// Pass 2: compose prefix chunks -> h_start, then replay chunk emitting y.
// Thread = (dg, n) in a 16x16 block; block = (b, chunk, d-group).
// ---------------------------------------------------------------------------
__global__ __launch_bounds__(256) void scan_pass1(
    const float* __restrict__ dt,    // [BL][512]
    const float* __restrict__ xc,    // [BL][512]
    const float* __restrict__ xdbl,  // [BL][48]  (B at +16)
    const float* __restrict__ Alog,  // [512][16]
    float2* __restrict__ Pq)         // [NC][B_][DI][DS]
{
    __shared__ float sdt[CH][16], sxc[CH][16], sB[CH][16];
    const int b   = blockIdx.x;
    const int c   = blockIdx.y;
    const int d0  = blockIdx.z * 16;
    const int tid = threadIdx.x;
    const int dg  = tid >> 4;
    const int n   = tid & 15;
    const int d   = d0 + dg;

    const float Adn = -__expf(Alog[d * DS + n]);

#pragma unroll
    for (int qq = 0; qq < 4; ++qq) {
        const int idx  = qq * 256 + tid;
        const int toff = idx >> 4;
        const int col  = idx & 15;
        const size_t row = (size_t)b * L_ + c * CH + toff;
        sdt[toff][col] = dt[row * DI + d0 + col];
        sxc[toff][col] = xc[row * DI + d0 + col];
        sB [toff][col] = xdbl[row * 48 + DTR + col];
    }
    __syncthreads();

    float P = 1.f, q = 0.f;
#pragma unroll 4
    for (int tt = 0; tt < CH; ++tt) {
        const float dtv = sdt[tt][dg];
        const float xv  = sxc[tt][dg];
        const float bv  = sB[tt][n];
        const float a   = __expf(dtv * Adn);
        const float u   = dtv * xv * bv;
        P *= a;
        q = fmaf(q, a, u);
    }
    Pq[((size_t)(c * B_ + b) * DI + d) * DS + n] = make_float2(P, q);
}

__global__ __launch_bounds__(256) void scan_pass2(
    const float* __restrict__ dt,    // [BL][512]
    const float* __restrict__ xc,    // [BL][512]
    const float* __restrict__ xdbl,  // [BL][48]  (B at +16, C at +32)
    const float* __restrict__ xz,    // [BL][1024] (z at +512)
    const float* __restrict__ Alog,  // [512][16]
    const float* __restrict__ Dsk,   // [512]
    const float2* __restrict__ Pq,   // [NC][B_][DI][DS]
    float* __restrict__ yout)        // [BL][512]
{
    __shared__ float sdt[CH][16], sxc[CH][16], sB[CH][16], sC[CH][16], sz[CH][16];
    const int b   = blockIdx.x;
    const int c   = blockIdx.y;
    const int d0  = blockIdx.z * 16;
    const int tid = threadIdx.x;
    const int dg  = tid >> 4;
    const int n   = tid & 15;
    const int d   = d0 + dg;

    const float Adn  = -__expf(Alog[d * DS + n]);
    const float dskd = Dsk[d];

#pragma unroll
    for (int qq = 0; qq < 4; ++qq) {
        const int idx  = qq * 256 + tid;
        const int toff = idx >> 4;
        const int col  = idx & 15;
        const size_t row = (size_t)b * L_ + c * CH + toff;
        sdt[toff][col] = dt[row * DI + d0 + col];
        sxc[toff][col] = xc[row * DI + d0 + col];
        sB [toff][col] = xdbl[row * 48 + DTR + col];
        sC [toff][col] = xdbl[row * 48 + DTR + DS + col];
        sz [toff][col] = xz[row * (2*DI) + DI + d0 + col];
    }

    // compose prefix chunks (global reads only; overlaps the staging latency)
    float h = 0.f;
    for (int j = 0; j < c; ++j) {
        const float2 pq = Pq[((size_t)(j * B_ + b) * DI + d) * DS + n];
        h = fmaf(h, pq.x, pq.y);
    }
    __syncthreads();

    for (int tt = 0; tt < CH; ++tt) {
        const float dtv = sdt[tt][dg];
        const float xv  = sxc[tt][dg];
        const float bv  = sB[tt][n];
        const float cv  = sC[tt][n];
        const float a   = __expf(dtv * Adn);
        h = fmaf(h, a, dtv * xv * bv);
        float y = h * cv;
        y += __shfl_xor(y, 1, 16);
        y += __shfl_xor(y, 2, 16);
        y += __shfl_xor(y, 4, 16);
        y += __shfl_xor(y, 8, 16);
        if (n == 0) {
            const float zv = sz[tt][dg];
            const float sz_ = zv / (1.f + __expf(-zv));
            yout[((size_t)b * L_ + c * CH + tt) * DI + d] = (y + xv * dskd) * sz_;
        }
    }
}

// ---------------------------------------------------------------------------
// mask mean over the INPUT dim
// ---------------------------------------------------------------------------
__global__ __launch_bounds__(256) void maskmean_kernel(
    const float* __restrict__ mask, float* __restrict__ m)
{
    const int row = blockIdx.x * 256 + threadIdx.x;    // BL
    const float* p = mask + (size_t)row * INPUT_;
    float s = 0.f;
#pragma unroll
    for (int k = 0; k < INPUT_; ++k) s += p[k];
    m[row] = s * (1.f / INPUT_);
}

// ---------------------------------------------------------------------------
// masked mean pool over L, two stage
// ---------------------------------------------------------------------------
__global__ __launch_bounds__(256) void pool_partial(
    const float* __restrict__ h, const float* __restrict__ m,
    float* __restrict__ partial, float* __restrict__ msum)
{
    const int b  = blockIdx.x;
    const int ch = blockIdx.y;
    const int c  = threadIdx.x;
    float acc = 0.f, ms = 0.f;
    const int l0 = ch * (L_ / PCH);
    for (int l = l0; l < l0 + (L_ / PCH); ++l) {
        const float mv = m[b * L_ + l];
        acc = fmaf(h[((size_t)b * L_ + l) * DM + c], mv, acc);
        ms += mv;
    }
    partial[((size_t)b * PCH + ch) * DM + c] = acc;
    if (c == 0) msum[b * PCH + ch] = ms;
}

__global__ __launch_bounds__(256) void pool_final(
    const float* __restrict__ partial, const float* __restrict__ msum,
    float* __restrict__ pooled)
{
    const int b = blockIdx.x;
    const int c = threadIdx.x;
    float acc = 0.f, ms = 0.f;
#pragma unroll
    for (int ch = 0; ch < PCH; ++ch) {
        acc += partial[((size_t)b * PCH + ch) * DM + c];
        ms  += msum[b * PCH + ch];
    }
    pooled[b * DM + c] = acc / (ms + 1e-8f);
}

// ---------------------------------------------------------------------------
// head: fc1 + exact GELU + fc2
// ---------------------------------------------------------------------------
__global__ __launch_bounds__(128) void head_kernel(
    const float* __restrict__ pooled,
    const float* __restrict__ fc1w, const float* __restrict__ fc1b,
    const float* __restrict__ fc2w, const float* __restrict__ fc2b,
    float* __restrict__ out)
{
    __shared__ float sp[DM];
    __shared__ float sh[128];
    const int b = blockIdx.x;
    const int j = threadIdx.x;
    sp[j]       = pooled[b * DM + j];
    sp[j + 128] = pooled[b * DM + j + 128];
    __syncthreads();
    float acc = fc1b[j];
    for (int k = 0; k < DM; ++k) acc = fmaf(sp[k], fc1w[j * DM + k], acc);
    const float g = 0.5f * acc * (1.f + erff(acc * 0.70710678118654752f));
    sh[j] = g * fc2w[j];
    __syncthreads();
    for (int s = 64; s > 0; s >>= 1) {
        if (j < s) sh[j] += sh[j + s];
        __syncthreads();
    }
    if (j == 0) out[b] = sh[0] + fc2b[0];
}

// ---------------------------------------------------------------------------
extern "C" void kernel_launch(void* const* d_in, const int* in_sizes, int n_in,
                              void* d_out, int out_size, void* d_ws, size_t ws_size,
                              hipStream_t stream)
{
    const float* x       = (const float*)d_in[0];
    const float* mask    = (const float*)d_in[1];
    const float* ipw     = (const float*)d_in[2];
    const float* ipb     = (const float*)d_in[3];
    const float* in_w    = (const float*)d_in[4];
    const float* conv_w  = (const float*)d_in[5];
    const float* conv_b  = (const float*)d_in[6];
    const float* xpw     = (const float*)d_in[7];
    const float* dtw     = (const float*)d_in[8];
    const float* dtb     = (const float*)d_in[9];
    const float* A_log   = (const float*)d_in[10];
    const float* D_skip  = (const float*)d_in[11];
    const float* out_w   = (const float*)d_in[12];
    const float* ln_g    = (const float*)d_in[13];
    const float* ln_b    = (const float*)d_in[14];
    const float* fc1w    = (const float*)d_in[15];
    const float* fc1b    = (const float*)d_in[16];
    const float* fc2w    = (const float*)d_in[17];
    const float* fc2b    = (const float*)d_in[18];
    float* outp = (float*)d_out;

    // workspace carve-up (bytes, 256-aligned)
    char* ws = (char*)d_ws;
    size_t off = 0;
    auto alloc = [&](size_t nfloats) {
        float* p = (float*)(ws + off);
        off += ((nfloats * 4 + 255) / 256) * 256;
        return p;
    };
    float*  hbuf    = alloc((size_t)BL * DM);        // residual stream
    float*  xln     = alloc((size_t)BL * DM);
    float*  xzbuf   = alloc((size_t)BL * 2 * DI);
    float*  xcbuf   = alloc((size_t)BL * DI);
    float*  xdbl    = alloc((size_t)BL * 48);
    float*  dtbuf   = alloc((size_t)BL * DI);
    float*  ycomb   = alloc((size_t)BL * DI);
    float*  mbuf    = alloc((size_t)BL);
    float*  pooled  = alloc((size_t)B_ * DM);
    float2* Pqbuf   = (float2*)alloc((size_t)NC * B_ * DI * DS * 2);
    float*  partial = alloc((size_t)B_ * PCH * DM);
    float*  msum    = alloc((size_t)B_ * PCH);
    (void)ws_size; (void)n_in; (void)in_sizes; (void)out_size;

    const dim3 blk(256);

    // input projection: h = x @ ipw.T + ipb   (M=BL, N=256, K=40)
    gemm_nt<<<dim3(BL/GBM, DM/GBN), blk, 0, stream>>>(
        x, INPUT_, ipw, INPUT_, ipb, nullptr, hbuf, DM, DM, INPUT_, 0);

    for (int i = 0; i < NL; ++i) {
        const float* in_wi  = in_w   + (size_t)i * 2 * DI * DM;
        const float* cwi    = conv_w + (size_t)i * DI * DC;
        const float* cbi    = conv_b + (size_t)i * DI;
        const float* xpwi   = xpw    + (size_t)i * 48 * DI;
        const float* dtwi   = dtw    + (size_t)i * DI * DTR;
        const float* dtbi   = dtb    + (size_t)i * DI;
        const float* Alogi  = A_log  + (size_t)i * DI * DS;
        const float* Dski   = D_skip + (size_t)i * DI;
        const float* owi    = out_w  + (size_t)i * DM * DI;
        const float* lngi   = ln_g   + (size_t)i * DM;
        const float* lnbi   = ln_b   + (size_t)i * DM;

        // layernorm
        ln_kernel<<<BL, 64, 0, stream>>>(hbuf, lngi, lnbi, xln);

        // xz = xln @ in_w.T  (N=1024, K=256)
        gemm_nt<<<dim3(BL/GBM, (2*DI)/GBN), blk, 0, stream>>>(
            xln, DM, in_wi, DM, nullptr, nullptr, xzbuf, 2*DI, 2*DI, DM, 0);

        // conv + silu -> xc
        conv_silu<<<(BL * DI) / 256, blk, 0, stream>>>(xzbuf, cwi, cbi, xcbuf);

        // x_dbl = xc @ xpw.T  (N=48, K=512)
        gemm_nt<<<dim3(BL/GBM, 1), blk, 0, stream>>>(
            xcbuf, DI, xpwi, DI, nullptr, nullptr, xdbl, 48, 48, DI, 0);

        // dt = softplus(x_dbl[:, :16] @ dtw.T + dtb)  (N=512, K=16)
        gemm_nt<<<dim3(BL/GBM, DI/GBN), blk, 0, stream>>>(
            xdbl, 48, dtwi, DTR, dtbi, nullptr, dtbuf, DI, DI, DTR, 1);

        // selective scan (chunk-parallel) -> ycomb = (y + xc*D) * silu(z)
        scan_pass1<<<dim3(B_, NC, DI/16), blk, 0, stream>>>(
            dtbuf, xcbuf, xdbl, Alogi, Pqbuf);
        scan_pass2<<<dim3(B_, NC, DI/16), blk, 0, stream>>>(
            dtbuf, xcbuf, xdbl, xzbuf, Alogi, Dski, Pqbuf, ycomb);

        // h += ycomb @ ow.T  (N=256, K=512)
        gemm_nt<<<dim3(BL/GBM, DM/GBN), blk, 0, stream>>>(
            ycomb, DI, owi, DI, nullptr, hbuf, hbuf, DM, DM, DI, 0);
    }

    maskmean_kernel<<<BL / 256, blk, 0, stream>>>(mask, mbuf);
    pool_partial<<<dim3(B_, PCH), blk, 0, stream>>>(hbuf, mbuf, partial, msum);
    pool_final<<<B_, blk, 0, stream>>>(partial, msum, pooled);
    head_kernel<<<B_, dim3(128), 0, stream>>>(pooled, fc1w, fc1b, fc2w, fc2b, outp);
}

// Round 3
// 1844.061 us; speedup vs baseline: 1.3611x; 1.2948x over previous
//
#include <hip/hip_runtime.h>
#include <math.h>

#define B_  16
#define L_  1024
#define INPUT_ 40
#define DM  256
#define DS  16
#define NL  4
#define DC  4
#define DI  512
#define DTR 16
#define BL  (B_ * L_)   // 16384
#define NC  16          // scan chunks
#define CH  64          // timesteps per chunk (NC*CH == L_)
#define PCH 16          // pool chunks over L

// ---------------------------------------------------------------------------
// Tiled f32 GEMM (large):  C = op(A @ W^T + bias), 128x128x16, 8x8/thread.
// ---------------------------------------------------------------------------
#define GBM 128
#define GBN 128
#define GBK 16

__global__ __launch_bounds__(256) void gemm_nt(
    const float* __restrict__ A, int lda,
    const float* __restrict__ W, int ldw,
    const float* __restrict__ bias,
    const float* __restrict__ Cin,   // residual or nullptr
    float* __restrict__ C, int ldc,
    int N, int K, int act)           // act: 0 none, 1 softplus
{
    __shared__ float As[GBK][GBM];
    __shared__ float Ws[GBK][GBN];

    const int tid = threadIdx.x;
    const int m0 = blockIdx.x * GBM;
    const int n0 = blockIdx.y * GBN;
    const int tx = tid & 15;
    const int ty = tid >> 4;
    const int r  = tid >> 1;         // 0..127 load row
    const int kq = (tid & 1) * 8;    // 0 or 8

    float acc[8][8];
#pragma unroll
    for (int i = 0; i < 8; ++i)
#pragma unroll
        for (int j = 0; j < 8; ++j) acc[i][j] = 0.f;

    for (int k0 = 0; k0 < K; k0 += GBK) {
        {
            const int row = m0 + r;
            if (k0 + kq + 7 < K) {
                const float4 v0 = *reinterpret_cast<const float4*>(&A[(size_t)row * lda + k0 + kq]);
                const float4 v1 = *reinterpret_cast<const float4*>(&A[(size_t)row * lda + k0 + kq + 4]);
                As[kq+0][r] = v0.x; As[kq+1][r] = v0.y; As[kq+2][r] = v0.z; As[kq+3][r] = v0.w;
                As[kq+4][r] = v1.x; As[kq+5][r] = v1.y; As[kq+6][r] = v1.z; As[kq+7][r] = v1.w;
            } else {
#pragma unroll
                for (int i = 0; i < 8; ++i)
                    As[kq+i][r] = (k0 + kq + i < K) ? A[(size_t)row * lda + k0 + kq + i] : 0.f;
            }
        }
        {
            const int row = n0 + r;
            if (row < N && k0 + kq + 7 < K) {
                const float4 v0 = *reinterpret_cast<const float4*>(&W[(size_t)row * ldw + k0 + kq]);
                const float4 v1 = *reinterpret_cast<const float4*>(&W[(size_t)row * ldw + k0 + kq + 4]);
                Ws[kq+0][r] = v0.x; Ws[kq+1][r] = v0.y; Ws[kq+2][r] = v0.z; Ws[kq+3][r] = v0.w;
                Ws[kq+4][r] = v1.x; Ws[kq+5][r] = v1.y; Ws[kq+6][r] = v1.z; Ws[kq+7][r] = v1.w;
            } else {
#pragma unroll
                for (int i = 0; i < 8; ++i)
                    Ws[kq+i][r] = (row < N && k0 + kq + i < K) ? W[(size_t)row * ldw + k0 + kq + i] : 0.f;
            }
        }
        __syncthreads();

#pragma unroll
        for (int k = 0; k < GBK; ++k) {
            const float4 a0 = *reinterpret_cast<const float4*>(&As[k][ty * 8]);
            const float4 a1 = *reinterpret_cast<const float4*>(&As[k][ty * 8 + 4]);
            const float4 b0 = *reinterpret_cast<const float4*>(&Ws[k][tx * 8]);
            const float4 b1 = *reinterpret_cast<const float4*>(&Ws[k][tx * 8 + 4]);
            const float av[8] = {a0.x, a0.y, a0.z, a0.w, a1.x, a1.y, a1.z, a1.w};
            const float bv[8] = {b0.x, b0.y, b0.z, b0.w, b1.x, b1.y, b1.z, b1.w};
#pragma unroll
            for (int i = 0; i < 8; ++i)
#pragma unroll
                for (int j = 0; j < 8; ++j)
                    acc[i][j] = fmaf(av[i], bv[j], acc[i][j]);
        }
        __syncthreads();
    }

#pragma unroll
    for (int i = 0; i < 8; ++i) {
        const int row = m0 + ty * 8 + i;
#pragma unroll
        for (int j = 0; j < 8; ++j) {
            const int col = n0 + tx * 8 + j;
            if (col < N) {
                float v = acc[i][j];
                if (bias) v += bias[col];
                if (act == 1) v = (v > 20.f) ? v : log1pf(expf(v));
                if (Cin) v += Cin[(size_t)row * ldc + col];
                C[(size_t)row * ldc + col] = v;
            }
        }
    }
}

// ---------------------------------------------------------------------------
// Tiled f32 GEMM (small): 64x64x16, 4x4/thread — for N<128 or tiny-K shapes.
// ---------------------------------------------------------------------------
#define SBM 64
#define SBN 64
#define SBK 16

__global__ __launch_bounds__(256) void gemm_nt_64(
    const float* __restrict__ A, int lda,
    const float* __restrict__ W, int ldw,
    const float* __restrict__ bias,
    const float* __restrict__ Cin,
    float* __restrict__ C, int ldc,
    int N, int K, int act)
{
    __shared__ float As[SBK][SBM];
    __shared__ float Ws[SBK][SBN];

    const int tid = threadIdx.x;
    const int m0 = blockIdx.x * SBM;
    const int n0 = blockIdx.y * SBN;
    const int tx = tid & 15;
    const int ty = tid >> 4;
    const int r  = tid >> 2;         // 0..63
    const int kq = (tid & 3) * 4;    // 0,4,8,12

    float acc[4][4];
#pragma unroll
    for (int i = 0; i < 4; ++i)
#pragma unroll
        for (int j = 0; j < 4; ++j) acc[i][j] = 0.f;

    for (int k0 = 0; k0 < K; k0 += SBK) {
        {
            const int row = m0 + r;
            if (k0 + kq + 3 < K) {
                const float4 v = *reinterpret_cast<const float4*>(&A[(size_t)row * lda + k0 + kq]);
                As[kq+0][r] = v.x; As[kq+1][r] = v.y; As[kq+2][r] = v.z; As[kq+3][r] = v.w;
            } else {
#pragma unroll
                for (int i = 0; i < 4; ++i)
                    As[kq+i][r] = (k0 + kq + i < K) ? A[(size_t)row * lda + k0 + kq + i] : 0.f;
            }
        }
        {
            const int row = n0 + r;
            if (row < N && k0 + kq + 3 < K) {
                const float4 v = *reinterpret_cast<const float4*>(&W[(size_t)row * ldw + k0 + kq]);
                Ws[kq+0][r] = v.x; Ws[kq+1][r] = v.y; Ws[kq+2][r] = v.z; Ws[kq+3][r] = v.w;
            } else {
#pragma unroll
                for (int i = 0; i < 4; ++i)
                    Ws[kq+i][r] = (row < N && k0 + kq + i < K) ? W[(size_t)row * ldw + k0 + kq + i] : 0.f;
            }
        }
        __syncthreads();

#pragma unroll
        for (int k = 0; k < SBK; ++k) {
            const float4 a = *reinterpret_cast<const float4*>(&As[k][ty * 4]);
            const float4 b = *reinterpret_cast<const float4*>(&Ws[k][tx * 4]);
            const float av[4] = {a.x, a.y, a.z, a.w};
            const float bv[4] = {b.x, b.y, b.z, b.w};
#pragma unroll
            for (int i = 0; i < 4; ++i)
#pragma unroll
                for (int j = 0; j < 4; ++j)
                    acc[i][j] = fmaf(av[i], bv[j], acc[i][j]);
        }
        __syncthreads();
    }

#pragma unroll
    for (int i = 0; i < 4; ++i) {
        const int row = m0 + ty * 4 + i;
#pragma unroll
        for (int j = 0; j < 4; ++j) {
            const int col = n0 + tx * 4 + j;
            if (col < N) {
                float v = acc[i][j];
                if (bias) v += bias[col];
                if (act == 1) v = (v > 20.f) ? v : log1pf(expf(v));
                if (Cin) v += Cin[(size_t)row * ldc + col];
                C[(size_t)row * ldc + col] = v;
            }
        }
    }
}

// ---------------------------------------------------------------------------
// LayerNorm: one wave per row of 256.
// ---------------------------------------------------------------------------
__global__ __launch_bounds__(64) void ln_kernel(
    const float* __restrict__ h, const float* __restrict__ g,
    const float* __restrict__ bb, float* __restrict__ out)
{
    const int row = blockIdx.x;
    const int lane = threadIdx.x;
    const float4 v = *reinterpret_cast<const float4*>(&h[(size_t)row * DM + lane * 4]);
    float s  = v.x + v.y + v.z + v.w;
    float s2 = v.x*v.x + v.y*v.y + v.z*v.z + v.w*v.w;
#pragma unroll
    for (int m = 1; m < 64; m <<= 1) {
        s  += __shfl_xor(s, m);
        s2 += __shfl_xor(s2, m);
    }
    const float mu  = s * (1.f / DM);
    const float var = s2 * (1.f / DM) - mu * mu;
    const float rs  = rsqrtf(var + 1e-5f);
    const float4 gv = *reinterpret_cast<const float4*>(&g[lane * 4]);
    const float4 bv = *reinterpret_cast<const float4*>(&bb[lane * 4]);
    float4 o;
    o.x = (v.x - mu) * rs * gv.x + bv.x;
    o.y = (v.y - mu) * rs * gv.y + bv.y;
    o.z = (v.z - mu) * rs * gv.z + bv.z;
    o.w = (v.w - mu) * rs * gv.w + bv.w;
    *reinterpret_cast<float4*>(&out[(size_t)row * DM + lane * 4]) = o;
}

// ---------------------------------------------------------------------------
// Causal depthwise conv (k=4) + bias + SiLU.
// ---------------------------------------------------------------------------
__global__ __launch_bounds__(256) void conv_silu(
    const float* __restrict__ xz, const float* __restrict__ cw,
    const float* __restrict__ cb, float* __restrict__ xc)
{
    const int idx = blockIdx.x * 256 + threadIdx.x;   // BL*512 total
    const int d   = idx & (DI - 1);
    const int row = idx >> 9;
    const int t   = row & (L_ - 1);
    const float w0 = cw[d*4+0], w1 = cw[d*4+1], w2 = cw[d*4+2], w3 = cw[d*4+3];
    const float* base = xz + (size_t)row * (2*DI) + d;
    float acc = cb[d] + w3 * base[0];
    if (t >= 1) acc = fmaf(w2, base[-(2*DI)],   acc);
    if (t >= 2) acc = fmaf(w1, base[-2*(2*DI)], acc);
    if (t >= 3) acc = fmaf(w0, base[-3*(2*DI)], acc);
    xc[idx] = acc / (1.f + __expf(-acc));
}

// ---------------------------------------------------------------------------
// Selective scan, chunk-parallel, n-in-registers.
// Thread = (b, chunk, d); h[16]/q[16] live in VGPRs; B/C broadcast from LDS;
// dt/xc/z coalesced from global.
// Pass 1: per chunk compute q[16] (scan with h0=0) and S = sum(dt).
//   Chunk transfer operator: h_end = exp(A*S)*h_start + q.
// Compose: serial over 16 chunks -> h0 per (c,b,d,n).
// Pass 2: replay chunk from h0, emit ycomb = (y + xc*D)*silu(z).
// ---------------------------------------------------------------------------
__global__ __launch_bounds__(256) void scan_pass1(
    const float* __restrict__ dt,    // [BL][512]
    const float* __restrict__ xc,    // [BL][512]
    const float* __restrict__ xdbl,  // [BL][48]  (B at +16)
    const float* __restrict__ Alog,  // [512][16]
    float* __restrict__ qbuf,        // [NC][B_][DI][DS]
    float* __restrict__ Sbuf)        // [NC][B_][DI]
{
    __shared__ float sB[CH][16];
    const int b   = blockIdx.x;
    const int c   = blockIdx.y;
    const int d   = blockIdx.z * 256 + threadIdx.x;
    const int tid = threadIdx.x;

    // stage B tile
#pragma unroll
    for (int qq = 0; qq < 4; ++qq) {
        const int idx  = qq * 256 + tid;
        const int toff = idx >> 4;
        const int col  = idx & 15;
        sB[toff][col] = xdbl[((size_t)b * L_ + c * CH + toff) * 48 + DTR + col];
    }

    float Ad[16];
#pragma unroll
    for (int n = 0; n < 16; ++n) Ad[n] = -__expf(Alog[d * DS + n]);

    __syncthreads();

    float q[16];
#pragma unroll
    for (int n = 0; n < 16; ++n) q[n] = 0.f;
    float S = 0.f;

    const size_t row0 = (size_t)b * L_ + c * CH;
    for (int tt = 0; tt < CH; ++tt) {
        const float dtv = dt[(row0 + tt) * DI + d];
        const float xv  = xc[(row0 + tt) * DI + d];
        const float u   = dtv * xv;
        S += dtv;
        const float4* Bt = reinterpret_cast<const float4*>(&sB[tt][0]);
        const float4 b0 = Bt[0], b1 = Bt[1], b2 = Bt[2], b3 = Bt[3];
        const float bv[16] = {b0.x,b0.y,b0.z,b0.w, b1.x,b1.y,b1.z,b1.w,
                              b2.x,b2.y,b2.z,b2.w, b3.x,b3.y,b3.z,b3.w};
#pragma unroll
        for (int n = 0; n < 16; ++n) {
            const float a = __expf(dtv * Ad[n]);
            q[n] = fmaf(q[n], a, u * bv[n]);
        }
    }

    float* qb = qbuf + ((size_t)(c * B_ + b) * DI + d) * DS;
#pragma unroll
    for (int n4 = 0; n4 < 4; ++n4)
        reinterpret_cast<float4*>(qb)[n4] =
            make_float4(q[n4*4+0], q[n4*4+1], q[n4*4+2], q[n4*4+3]);
    Sbuf[(size_t)(c * B_ + b) * DI + d] = S;
}

__global__ __launch_bounds__(256) void scan_compose(
    const float* __restrict__ qbuf,  // [NC][B_][DI][DS]
    const float* __restrict__ Sbuf,  // [NC][B_][DI]
    const float* __restrict__ Alog,  // [512][16]
    float* __restrict__ h0buf)       // [NC][B_][DI][DS]
{
    const int gid = blockIdx.x * 256 + threadIdx.x;   // B_*DI*DS = 131072
    const int n = gid & 15;
    const int d = (gid >> 4) & (DI - 1);
    const int b = gid >> 13;
    const float Adn = -__expf(Alog[d * DS + n]);
    float h = 0.f;
    for (int c = 0; c < NC; ++c) {
        const size_t base = (size_t)(c * B_ + b) * DI + d;
        h0buf[base * DS + n] = h;
        const float S = Sbuf[base];
        const float q = qbuf[base * DS + n];
        h = fmaf(h, __expf(Adn * S), q);
    }
}

__global__ __launch_bounds__(256) void scan_pass2(
    const float* __restrict__ dt,    // [BL][512]
    const float* __restrict__ xc,    // [BL][512]
    const float* __restrict__ xdbl,  // [BL][48]  (B at +16, C at +32)
    const float* __restrict__ xz,    // [BL][1024] (z at +512)
    const float* __restrict__ Alog,  // [512][16]
    const float* __restrict__ Dsk,   // [512]
    const float* __restrict__ h0buf, // [NC][B_][DI][DS]
    float* __restrict__ yout)        // [BL][512]
{
    __shared__ float sB[CH][16];
    __shared__ float sC[CH][16];
    const int b   = blockIdx.x;
    const int c   = blockIdx.y;
    const int d   = blockIdx.z * 256 + threadIdx.x;
    const int tid = threadIdx.x;

#pragma unroll
    for (int qq = 0; qq < 4; ++qq) {
        const int idx  = qq * 256 + tid;
        const int toff = idx >> 4;
        const int col  = idx & 15;
        const size_t row = (size_t)b * L_ + c * CH + toff;
        sB[toff][col] = xdbl[row * 48 + DTR + col];
        sC[toff][col] = xdbl[row * 48 + DTR + DS + col];
    }

    float Ad[16];
#pragma unroll
    for (int n = 0; n < 16; ++n) Ad[n] = -__expf(Alog[d * DS + n]);
    const float dskd = Dsk[d];

    float h[16];
    const float* h0 = h0buf + ((size_t)(c * B_ + b) * DI + d) * DS;
#pragma unroll
    for (int n4 = 0; n4 < 4; ++n4) {
        const float4 v = reinterpret_cast<const float4*>(h0)[n4];
        h[n4*4+0] = v.x; h[n4*4+1] = v.y; h[n4*4+2] = v.z; h[n4*4+3] = v.w;
    }

    __syncthreads();

    const size_t row0 = (size_t)b * L_ + c * CH;
    for (int tt = 0; tt < CH; ++tt) {
        const size_t row = row0 + tt;
        const float dtv = dt[row * DI + d];
        const float xv  = xc[row * DI + d];
        const float zv  = xz[row * (2*DI) + DI + d];
        const float u   = dtv * xv;

        const float4* Bt = reinterpret_cast<const float4*>(&sB[tt][0]);
        const float4* Ct = reinterpret_cast<const float4*>(&sC[tt][0]);
        const float4 b0 = Bt[0], b1 = Bt[1], b2 = Bt[2], b3 = Bt[3];
        const float4 c0 = Ct[0], c1 = Ct[1], c2 = Ct[2], c3 = Ct[3];
        const float bv[16] = {b0.x,b0.y,b0.z,b0.w, b1.x,b1.y,b1.z,b1.w,
                              b2.x,b2.y,b2.z,b2.w, b3.x,b3.y,b3.z,b3.w};
        const float cv[16] = {c0.x,c0.y,c0.z,c0.w, c1.x,c1.y,c1.z,c1.w,
                              c2.x,c2.y,c2.z,c2.w, c3.x,c3.y,c3.z,c3.w};

        float y0 = 0.f, y1 = 0.f, y2 = 0.f, y3 = 0.f;
#pragma unroll
        for (int n = 0; n < 4; ++n) {
            const float a0 = __expf(dtv * Ad[n]);
            const float a1 = __expf(dtv * Ad[n+4]);
            const float a2 = __expf(dtv * Ad[n+8]);
            const float a3 = __expf(dtv * Ad[n+12]);
            h[n]    = fmaf(h[n],    a0, u * bv[n]);
            h[n+4]  = fmaf(h[n+4],  a1, u * bv[n+4]);
            h[n+8]  = fmaf(h[n+8],  a2, u * bv[n+8]);
            h[n+12] = fmaf(h[n+12], a3, u * bv[n+12]);
            y0 = fmaf(h[n],    cv[n],    y0);
            y1 = fmaf(h[n+4],  cv[n+4],  y1);
            y2 = fmaf(h[n+8],  cv[n+8],  y2);
            y3 = fmaf(h[n+12], cv[n+12], y3);
        }
        const float y = (y0 + y1) + (y2 + y3);
        const float sz_ = zv / (1.f + __expf(-zv));
        yout[row * DI + d] = (y + xv * dskd) * sz_;
    }
}

// ---------------------------------------------------------------------------
// mask mean over the INPUT dim
// ---------------------------------------------------------------------------
__global__ __launch_bounds__(256) void maskmean_kernel(
    const float* __restrict__ mask, float* __restrict__ m)
{
    const int row = blockIdx.x * 256 + threadIdx.x;    // BL
    const float* p = mask + (size_t)row * INPUT_;
    float s = 0.f;
#pragma unroll
    for (int k = 0; k < INPUT_; ++k) s += p[k];
    m[row] = s * (1.f / INPUT_);
}

// ---------------------------------------------------------------------------
// masked mean pool over L, two stage
// ---------------------------------------------------------------------------
__global__ __launch_bounds__(256) void pool_partial(
    const float* __restrict__ h, const float* __restrict__ m,
    float* __restrict__ partial, float* __restrict__ msum)
{
    const int b  = blockIdx.x;
    const int ch = blockIdx.y;
    const int c  = threadIdx.x;
    float acc = 0.f, ms = 0.f;
    const int l0 = ch * (L_ / PCH);
    for (int l = l0; l < l0 + (L_ / PCH); ++l) {
        const float mv = m[b * L_ + l];
        acc = fmaf(h[((size_t)b * L_ + l) * DM + c], mv, acc);
        ms += mv;
    }
    partial[((size_t)b * PCH + ch) * DM + c] = acc;
    if (c == 0) msum[b * PCH + ch] = ms;
}

__global__ __launch_bounds__(256) void pool_final(
    const float* __restrict__ partial, const float* __restrict__ msum,
    float* __restrict__ pooled)
{
    const int b = blockIdx.x;
    const int c = threadIdx.x;
    float acc = 0.f, ms = 0.f;
#pragma unroll
    for (int ch = 0; ch < PCH; ++ch) {
        acc += partial[((size_t)b * PCH + ch) * DM + c];
        ms  += msum[b * PCH + ch];
    }
    pooled[b * DM + c] = acc / (ms + 1e-8f);
}

// ---------------------------------------------------------------------------
// head: fc1 + exact GELU + fc2
// ---------------------------------------------------------------------------
__global__ __launch_bounds__(128) void head_kernel(
    const float* __restrict__ pooled,
    const float* __restrict__ fc1w, const float* __restrict__ fc1b,
    const float* __restrict__ fc2w, const float* __restrict__ fc2b,
    float* __restrict__ out)
{
    __shared__ float sp[DM];
    __shared__ float sh[128];
    const int b = blockIdx.x;
    const int j = threadIdx.x;
    sp[j]       = pooled[b * DM + j];
    sp[j + 128] = pooled[b * DM + j + 128];
    __syncthreads();
    float acc = fc1b[j];
    for (int k = 0; k < DM; ++k) acc = fmaf(sp[k], fc1w[j * DM + k], acc);
    const float g = 0.5f * acc * (1.f + erff(acc * 0.70710678118654752f));
    sh[j] = g * fc2w[j];
    __syncthreads();
    for (int s = 64; s > 0; s >>= 1) {
        if (j < s) sh[j] += sh[j + s];
        __syncthreads();
    }
    if (j == 0) out[b] = sh[0] + fc2b[0];
}

// ---------------------------------------------------------------------------
extern "C" void kernel_launch(void* const* d_in, const int* in_sizes, int n_in,
                              void* d_out, int out_size, void* d_ws, size_t ws_size,
                              hipStream_t stream)
{
    const float* x       = (const float*)d_in[0];
    const float* mask    = (const float*)d_in[1];
    const float* ipw     = (const float*)d_in[2];
    const float* ipb     = (const float*)d_in[3];
    const float* in_w    = (const float*)d_in[4];
    const float* conv_w  = (const float*)d_in[5];
    const float* conv_b  = (const float*)d_in[6];
    const float* xpw     = (const float*)d_in[7];
    const float* dtw     = (const float*)d_in[8];
    const float* dtb     = (const float*)d_in[9];
    const float* A_log   = (const float*)d_in[10];
    const float* D_skip  = (const float*)d_in[11];
    const float* out_w   = (const float*)d_in[12];
    const float* ln_g    = (const float*)d_in[13];
    const float* ln_b    = (const float*)d_in[14];
    const float* fc1w    = (const float*)d_in[15];
    const float* fc1b    = (const float*)d_in[16];
    const float* fc2w    = (const float*)d_in[17];
    const float* fc2b    = (const float*)d_in[18];
    float* outp = (float*)d_out;

    char* ws = (char*)d_ws;
    size_t off = 0;
    auto alloc = [&](size_t nfloats) {
        float* p = (float*)(ws + off);
        off += ((nfloats * 4 + 255) / 256) * 256;
        return p;
    };
    float*  hbuf    = alloc((size_t)BL * DM);
    float*  xln     = alloc((size_t)BL * DM);
    float*  xzbuf   = alloc((size_t)BL * 2 * DI);
    float*  xcbuf   = alloc((size_t)BL * DI);
    float*  xdbl    = alloc((size_t)BL * 48);
    float*  dtbuf   = alloc((size_t)BL * DI);
    float*  ycomb   = alloc((size_t)BL * DI);
    float*  mbuf    = alloc((size_t)BL);
    float*  pooled  = alloc((size_t)B_ * DM);
    float*  qbuf    = alloc((size_t)NC * B_ * DI * DS);
    float*  Sbuf    = alloc((size_t)NC * B_ * DI);
    float*  h0buf   = alloc((size_t)NC * B_ * DI * DS);
    float*  partial = alloc((size_t)B_ * PCH * DM);
    float*  msum    = alloc((size_t)B_ * PCH);
    (void)ws_size; (void)n_in; (void)in_sizes; (void)out_size;

    const dim3 blk(256);

    // input projection: h = x @ ipw.T + ipb   (M=BL, N=256, K=40)
    gemm_nt_64<<<dim3(BL/SBM, DM/SBN), blk, 0, stream>>>(
        x, INPUT_, ipw, INPUT_, ipb, nullptr, hbuf, DM, DM, INPUT_, 0);

    for (int i = 0; i < NL; ++i) {
        const float* in_wi  = in_w   + (size_t)i * 2 * DI * DM;
        const float* cwi    = conv_w + (size_t)i * DI * DC;
        const float* cbi    = conv_b + (size_t)i * DI;
        const float* xpwi   = xpw    + (size_t)i * 48 * DI;
        const float* dtwi   = dtw    + (size_t)i * DI * DTR;
        const float* dtbi   = dtb    + (size_t)i * DI;
        const float* Alogi  = A_log  + (size_t)i * DI * DS;
        const float* Dski   = D_skip + (size_t)i * DI;
        const float* owi    = out_w  + (size_t)i * DM * DI;
        const float* lngi   = ln_g   + (size_t)i * DM;
        const float* lnbi   = ln_b   + (size_t)i * DM;

        ln_kernel<<<BL, 64, 0, stream>>>(hbuf, lngi, lnbi, xln);

        // xz = xln @ in_w.T  (N=1024, K=256)
        gemm_nt<<<dim3(BL/GBM, (2*DI)/GBN), blk, 0, stream>>>(
            xln, DM, in_wi, DM, nullptr, nullptr, xzbuf, 2*DI, 2*DI, DM, 0);

        conv_silu<<<(BL * DI) / 256, blk, 0, stream>>>(xzbuf, cwi, cbi, xcbuf);

        // x_dbl = xc @ xpw.T  (N=48, K=512)
        gemm_nt_64<<<dim3(BL/SBM, 1), blk, 0, stream>>>(
            xcbuf, DI, xpwi, DI, nullptr, nullptr, xdbl, 48, 48, DI, 0);

        // dt = softplus(x_dbl[:, :16] @ dtw.T + dtb)  (N=512, K=16)
        gemm_nt_64<<<dim3(BL/SBM, DI/SBN), blk, 0, stream>>>(
            xdbl, 48, dtwi, DTR, dtbi, nullptr, dtbuf, DI, DI, DTR, 1);

        // selective scan (chunk-parallel, n-in-registers)
        scan_pass1<<<dim3(B_, NC, DI/256), blk, 0, stream>>>(
            dtbuf, xcbuf, xdbl, Alogi, qbuf, Sbuf);
        scan_compose<<<(B_ * DI * DS) / 256, blk, 0, stream>>>(
            qbuf, Sbuf, Alogi, h0buf);
        scan_pass2<<<dim3(B_, NC, DI/256), blk, 0, stream>>>(
            dtbuf, xcbuf, xdbl, xzbuf, Alogi, Dski, h0buf, ycomb);

        // h += ycomb @ ow.T  (N=256, K=512)
        gemm_nt<<<dim3(BL/GBM, DM/GBN), blk, 0, stream>>>(
            ycomb, DI, owi, DI, nullptr, hbuf, hbuf, DM, DM, DI, 0);
    }

    maskmean_kernel<<<BL / 256, blk, 0, stream>>>(mask, mbuf);
    pool_partial<<<dim3(B_, PCH), blk, 0, stream>>>(hbuf, mbuf, partial, msum);
    pool_final<<<B_, blk, 0, stream>>>(partial, msum, pooled);
    head_kernel<<<B_, dim3(128), 0, stream>>>(pooled, fc1w, fc1b, fc2w, fc2b, outp);
}

// Round 4
// 1160.413 us; speedup vs baseline: 2.1630x; 1.5891x over previous
//
#include <hip/hip_runtime.h>
#include <math.h>

#define B_  16
#define L_  1024
#define INPUT_ 40
#define DM  256
#define DS  16
#define NL  4
#define DC  4
#define DI  512
#define DTR 16
#define BL  (B_ * L_)   // 16384
#define NC  16          // scan chunks
#define CH  64          // timesteps per chunk
#define PCH 16          // pool chunks over L

using bf16x8 = __attribute__((ext_vector_type(8))) short;
using f32x4  = __attribute__((ext_vector_type(4))) float;

__device__ __forceinline__ ushort f2bf(float x) {
    unsigned u = __float_as_uint(x);
    u += 0x7FFFu + ((u >> 16) & 1u);          // round-to-nearest-even
    return (ushort)(u >> 16);
}
__device__ __forceinline__ float bf2f(ushort h) {
    return __uint_as_float((unsigned)h << 16);
}

// ---------------------------------------------------------------------------
// split f32 -> (hi, lo) bf16 arrays, 4 elems/thread
// ---------------------------------------------------------------------------
__global__ __launch_bounds__(256) void cvt_split(
    const float* __restrict__ in, ushort* __restrict__ oh,
    ushort* __restrict__ ol, int n4)
{
    const int i = blockIdx.x * 256 + threadIdx.x;
    if (i >= n4) return;
    const float4 v = reinterpret_cast<const float4*>(in)[i];
    ushort4 h, l;
    h.x = f2bf(v.x); l.x = f2bf(v.x - bf2f(h.x));
    h.y = f2bf(v.y); l.y = f2bf(v.y - bf2f(h.y));
    h.z = f2bf(v.z); l.z = f2bf(v.z - bf2f(h.z));
    h.w = f2bf(v.w); l.w = f2bf(v.w - bf2f(h.w));
    reinterpret_cast<ushort4*>(oh)[i] = h;
    reinterpret_cast<ushort4*>(ol)[i] = l;
}

// ---------------------------------------------------------------------------
// MFMA bf16x3 GEMM: C[m][n] = sum_k A[m][k]*W[n][k] (+ Cin), A,W as hi/lo bf16.
// 128x128 tile, BK=32, 256 threads = 4 waves (2x2 of 64x64), 16 MFMA frags/wave.
// LDS slot-XOR swizzle: LDS[row][s] = global[row][s ^ (row&3)] (16B slots).
// ---------------------------------------------------------------------------
__global__ __launch_bounds__(256) void gemm_mfma(
    const ushort* __restrict__ Ah, const ushort* __restrict__ Al,
    const ushort* __restrict__ Wh, const ushort* __restrict__ Wl,
    const float* __restrict__ Cin, float* __restrict__ C,
    int ldc, int K)
{
    __shared__ ushort sA[2][128][32];
    __shared__ ushort sW[2][128][32];

    const int tid  = threadIdx.x;
    const int m0   = blockIdx.x * 128;
    const int n0   = blockIdx.y * 128;
    const int lane = tid & 63;
    const int wv   = tid >> 6;
    const int wm   = wv >> 1, wn = wv & 1;

    // ---- staging map: thread -> row rr, slots ss, ss+1 ----
    const int rr  = tid >> 1;
    const int ss  = (tid & 1) * 2;
    const int gsa = (ss ^ (rr & 3)) * 8;        // pre-swizzled global k-slot
    const int gsb = ((ss + 1) ^ (rr & 3)) * 8;
    const ushort* pAh0 = Ah + (size_t)(m0 + rr) * K + gsa;
    const ushort* pAh1 = Ah + (size_t)(m0 + rr) * K + gsb;
    const ushort* pAl0 = Al + (size_t)(m0 + rr) * K + gsa;
    const ushort* pAl1 = Al + (size_t)(m0 + rr) * K + gsb;
    const ushort* pWh0 = Wh + (size_t)(n0 + rr) * K + gsa;
    const ushort* pWh1 = Wh + (size_t)(n0 + rr) * K + gsb;
    const ushort* pWl0 = Wl + (size_t)(n0 + rr) * K + gsa;
    const ushort* pWl1 = Wl + (size_t)(n0 + rr) * K + gsb;

    // ---- compute-read LDS pointers (constant across k-steps) ----
    const int ks = lane >> 4;      // k-slot 0..3 (8 bf16 each)
    const int lr = lane & 15;      // fragment row/col
    const ushort* rA[2][4];
    const ushort* rB[2][4];
#pragma unroll
    for (int f = 0; f < 4; ++f) {
        const int ar = wm * 64 + f * 16 + lr;
        const int as = (ks ^ (ar & 3)) * 8;
        rA[0][f] = &sA[0][ar][as];
        rA[1][f] = &sA[1][ar][as];
        const int bc = wn * 64 + f * 16 + lr;
        const int bs = (ks ^ (bc & 3)) * 8;
        rB[0][f] = &sW[0][bc][bs];
        rB[1][f] = &sW[1][bc][bs];
    }

    f32x4 acc[4][4];
#pragma unroll
    for (int i = 0; i < 4; ++i)
#pragma unroll
        for (int j = 0; j < 4; ++j)
            acc[i][j] = (f32x4){0.f, 0.f, 0.f, 0.f};

    for (int k0 = 0; k0 < K; k0 += 32) {
        const float4 vah0 = *reinterpret_cast<const float4*>(pAh0 + k0);
        const float4 vah1 = *reinterpret_cast<const float4*>(pAh1 + k0);
        const float4 val0 = *reinterpret_cast<const float4*>(pAl0 + k0);
        const float4 val1 = *reinterpret_cast<const float4*>(pAl1 + k0);
        const float4 vwh0 = *reinterpret_cast<const float4*>(pWh0 + k0);
        const float4 vwh1 = *reinterpret_cast<const float4*>(pWh1 + k0);
        const float4 vwl0 = *reinterpret_cast<const float4*>(pWl0 + k0);
        const float4 vwl1 = *reinterpret_cast<const float4*>(pWl1 + k0);
        __syncthreads();   // previous iteration's ds_reads complete
        *reinterpret_cast<float4*>(&sA[0][rr][ss * 8])       = vah0;
        *reinterpret_cast<float4*>(&sA[0][rr][(ss + 1) * 8]) = vah1;
        *reinterpret_cast<float4*>(&sA[1][rr][ss * 8])       = val0;
        *reinterpret_cast<float4*>(&sA[1][rr][(ss + 1) * 8]) = val1;
        *reinterpret_cast<float4*>(&sW[0][rr][ss * 8])       = vwh0;
        *reinterpret_cast<float4*>(&sW[0][rr][(ss + 1) * 8]) = vwh1;
        *reinterpret_cast<float4*>(&sW[1][rr][ss * 8])       = vwl0;
        *reinterpret_cast<float4*>(&sW[1][rr][(ss + 1) * 8]) = vwl1;
        __syncthreads();   // staging visible

        bf16x8 ah[4], al[4], bh[4], bl[4];
#pragma unroll
        for (int f = 0; f < 4; ++f) {
            ah[f] = *reinterpret_cast<const bf16x8*>(rA[0][f]);
            al[f] = *reinterpret_cast<const bf16x8*>(rA[1][f]);
            bh[f] = *reinterpret_cast<const bf16x8*>(rB[0][f]);
            bl[f] = *reinterpret_cast<const bf16x8*>(rB[1][f]);
        }
#pragma unroll
        for (int mi = 0; mi < 4; ++mi)
#pragma unroll
            for (int ni = 0; ni < 4; ++ni) {
                acc[mi][ni] = __builtin_amdgcn_mfma_f32_16x16x32_bf16(al[mi], bh[ni], acc[mi][ni], 0, 0, 0);
                acc[mi][ni] = __builtin_amdgcn_mfma_f32_16x16x32_bf16(ah[mi], bl[ni], acc[mi][ni], 0, 0, 0);
                acc[mi][ni] = __builtin_amdgcn_mfma_f32_16x16x32_bf16(ah[mi], bh[ni], acc[mi][ni], 0, 0, 0);
            }
    }

    // epilogue: C/D layout col=lane&15, row=(lane>>4)*4+reg
#pragma unroll
    for (int mi = 0; mi < 4; ++mi) {
        const int gr0 = m0 + wm * 64 + mi * 16 + ks * 4;
#pragma unroll
        for (int ni = 0; ni < 4; ++ni) {
            const int gc = n0 + wn * 64 + ni * 16 + lr;
#pragma unroll
            for (int rg = 0; rg < 4; ++rg) {
                float v = acc[mi][ni][rg];
                const size_t idx = (size_t)(gr0 + rg) * ldc + gc;
                if (Cin) v += Cin[idx];
                C[idx] = v;
            }
        }
    }
}

// ---------------------------------------------------------------------------
// Tiled f32 GEMM (small shapes): 64x64x16, 4x4/thread.
// ---------------------------------------------------------------------------
#define SBM 64
#define SBN 64
#define SBK 16

__global__ __launch_bounds__(256) void gemm_nt_64(
    const float* __restrict__ A, int lda,
    const float* __restrict__ W, int ldw,
    const float* __restrict__ bias,
    const float* __restrict__ Cin,
    float* __restrict__ C, int ldc,
    int N, int K, int act)
{
    __shared__ float As[SBK][SBM];
    __shared__ float Ws[SBK][SBN];

    const int tid = threadIdx.x;
    const int m0 = blockIdx.x * SBM;
    const int n0 = blockIdx.y * SBN;
    const int tx = tid & 15;
    const int ty = tid >> 4;
    const int r  = tid >> 2;
    const int kq = (tid & 3) * 4;

    float acc[4][4];
#pragma unroll
    for (int i = 0; i < 4; ++i)
#pragma unroll
        for (int j = 0; j < 4; ++j) acc[i][j] = 0.f;

    for (int k0 = 0; k0 < K; k0 += SBK) {
        {
            const int row = m0 + r;
            if (k0 + kq + 3 < K) {
                const float4 v = *reinterpret_cast<const float4*>(&A[(size_t)row * lda + k0 + kq]);
                As[kq+0][r] = v.x; As[kq+1][r] = v.y; As[kq+2][r] = v.z; As[kq+3][r] = v.w;
            } else {
#pragma unroll
                for (int i = 0; i < 4; ++i)
                    As[kq+i][r] = (k0 + kq + i < K) ? A[(size_t)row * lda + k0 + kq + i] : 0.f;
            }
        }
        {
            const int row = n0 + r;
            if (row < N && k0 + kq + 3 < K) {
                const float4 v = *reinterpret_cast<const float4*>(&W[(size_t)row * ldw + k0 + kq]);
                Ws[kq+0][r] = v.x; Ws[kq+1][r] = v.y; Ws[kq+2][r] = v.z; Ws[kq+3][r] = v.w;
            } else {
#pragma unroll
                for (int i = 0; i < 4; ++i)
                    Ws[kq+i][r] = (row < N && k0 + kq + i < K) ? W[(size_t)row * ldw + k0 + kq + i] : 0.f;
            }
        }
        __syncthreads();

#pragma unroll
        for (int k = 0; k < SBK; ++k) {
            const float4 a = *reinterpret_cast<const float4*>(&As[k][ty * 4]);
            const float4 b = *reinterpret_cast<const float4*>(&Ws[k][tx * 4]);
            const float av[4] = {a.x, a.y, a.z, a.w};
            const float bv[4] = {b.x, b.y, b.z, b.w};
#pragma unroll
            for (int i = 0; i < 4; ++i)
#pragma unroll
                for (int j = 0; j < 4; ++j)
                    acc[i][j] = fmaf(av[i], bv[j], acc[i][j]);
        }
        __syncthreads();
    }

#pragma unroll
    for (int i = 0; i < 4; ++i) {
        const int row = m0 + ty * 4 + i;
#pragma unroll
        for (int j = 0; j < 4; ++j) {
            const int col = n0 + tx * 4 + j;
            if (col < N) {
                float v = acc[i][j];
                if (bias) v += bias[col];
                if (act == 1) v = (v > 20.f) ? v : log1pf(expf(v));
                if (Cin) v += Cin[(size_t)row * ldc + col];
                C[(size_t)row * ldc + col] = v;
            }
        }
    }
}

// ---------------------------------------------------------------------------
// LayerNorm: one wave per row of 256; emits hi/lo bf16 for the MFMA GEMM.
// ---------------------------------------------------------------------------
__global__ __launch_bounds__(64) void ln_kernel(
    const float* __restrict__ h, const float* __restrict__ g,
    const float* __restrict__ bb,
    ushort* __restrict__ oh, ushort* __restrict__ ol)
{
    const int row = blockIdx.x;
    const int lane = threadIdx.x;
    const float4 v = *reinterpret_cast<const float4*>(&h[(size_t)row * DM + lane * 4]);
    float s  = v.x + v.y + v.z + v.w;
    float s2 = v.x*v.x + v.y*v.y + v.z*v.z + v.w*v.w;
#pragma unroll
    for (int m = 1; m < 64; m <<= 1) {
        s  += __shfl_xor(s, m);
        s2 += __shfl_xor(s2, m);
    }
    const float mu  = s * (1.f / DM);
    const float var = s2 * (1.f / DM) - mu * mu;
    const float rs  = rsqrtf(var + 1e-5f);
    const float4 gv = *reinterpret_cast<const float4*>(&g[lane * 4]);
    const float4 bv = *reinterpret_cast<const float4*>(&bb[lane * 4]);
    float o0 = (v.x - mu) * rs * gv.x + bv.x;
    float o1 = (v.y - mu) * rs * gv.y + bv.y;
    float o2 = (v.z - mu) * rs * gv.z + bv.z;
    float o3 = (v.w - mu) * rs * gv.w + bv.w;
    ushort4 hv, lv;
    hv.x = f2bf(o0); lv.x = f2bf(o0 - bf2f(hv.x));
    hv.y = f2bf(o1); lv.y = f2bf(o1 - bf2f(hv.y));
    hv.z = f2bf(o2); lv.z = f2bf(o2 - bf2f(hv.z));
    hv.w = f2bf(o3); lv.w = f2bf(o3 - bf2f(hv.w));
    *reinterpret_cast<ushort4*>(&oh[(size_t)row * DM + lane * 4]) = hv;
    *reinterpret_cast<ushort4*>(&ol[(size_t)row * DM + lane * 4]) = lv;
}

// ---------------------------------------------------------------------------
// Causal depthwise conv (k=4) + bias + SiLU.
// ---------------------------------------------------------------------------
__global__ __launch_bounds__(256) void conv_silu(
    const float* __restrict__ xz, const float* __restrict__ cw,
    const float* __restrict__ cb, float* __restrict__ xc)
{
    const int idx = blockIdx.x * 256 + threadIdx.x;
    const int d   = idx & (DI - 1);
    const int row = idx >> 9;
    const int t   = row & (L_ - 1);
    const float w0 = cw[d*4+0], w1 = cw[d*4+1], w2 = cw[d*4+2], w3 = cw[d*4+3];
    const float* base = xz + (size_t)row * (2*DI) + d;
    float acc = cb[d] + w3 * base[0];
    if (t >= 1) acc = fmaf(w2, base[-(2*DI)],   acc);
    if (t >= 2) acc = fmaf(w1, base[-2*(2*DI)], acc);
    if (t >= 3) acc = fmaf(w0, base[-3*(2*DI)], acc);
    xc[idx] = acc / (1.f + __expf(-acc));
}

// ---------------------------------------------------------------------------
// Selective scan, chunk-parallel, n-in-registers (see round-3 notes).
// ---------------------------------------------------------------------------
__global__ __launch_bounds__(256) void scan_pass1(
    const float* __restrict__ dt, const float* __restrict__ xc,
    const float* __restrict__ xdbl, const float* __restrict__ Alog,
    float* __restrict__ qbuf, float* __restrict__ Sbuf)
{
    __shared__ float sB[CH][16];
    const int b   = blockIdx.x;
    const int c   = blockIdx.y;
    const int d   = blockIdx.z * 256 + threadIdx.x;
    const int tid = threadIdx.x;

#pragma unroll
    for (int qq = 0; qq < 4; ++qq) {
        const int idx  = qq * 256 + tid;
        const int toff = idx >> 4;
        const int col  = idx & 15;
        sB[toff][col] = xdbl[((size_t)b * L_ + c * CH + toff) * 48 + DTR + col];
    }

    float Ad[16];
#pragma unroll
    for (int n = 0; n < 16; ++n) Ad[n] = -__expf(Alog[d * DS + n]);

    __syncthreads();

    float q[16];
#pragma unroll
    for (int n = 0; n < 16; ++n) q[n] = 0.f;
    float S = 0.f;

    const size_t row0 = (size_t)b * L_ + c * CH;
    for (int tt = 0; tt < CH; ++tt) {
        const float dtv = dt[(row0 + tt) * DI + d];
        const float xv  = xc[(row0 + tt) * DI + d];
        const float u   = dtv * xv;
        S += dtv;
        const float4* Bt = reinterpret_cast<const float4*>(&sB[tt][0]);
        const float4 b0 = Bt[0], b1 = Bt[1], b2 = Bt[2], b3 = Bt[3];
        const float bv[16] = {b0.x,b0.y,b0.z,b0.w, b1.x,b1.y,b1.z,b1.w,
                              b2.x,b2.y,b2.z,b2.w, b3.x,b3.y,b3.z,b3.w};
#pragma unroll
        for (int n = 0; n < 16; ++n) {
            const float a = __expf(dtv * Ad[n]);
            q[n] = fmaf(q[n], a, u * bv[n]);
        }
    }

    float* qb = qbuf + ((size_t)(c * B_ + b) * DI + d) * DS;
#pragma unroll
    for (int n4 = 0; n4 < 4; ++n4)
        reinterpret_cast<float4*>(qb)[n4] =
            make_float4(q[n4*4+0], q[n4*4+1], q[n4*4+2], q[n4*4+3]);
    Sbuf[(size_t)(c * B_ + b) * DI + d] = S;
}

__global__ __launch_bounds__(256) void scan_compose(
    const float* __restrict__ qbuf, const float* __restrict__ Sbuf,
    const float* __restrict__ Alog, float* __restrict__ h0buf)
{
    const int gid = blockIdx.x * 256 + threadIdx.x;
    const int n = gid & 15;
    const int d = (gid >> 4) & (DI - 1);
    const int b = gid >> 13;
    const float Adn = -__expf(Alog[d * DS + n]);
    float h = 0.f;
    for (int c = 0; c < NC; ++c) {
        const size_t base = (size_t)(c * B_ + b) * DI + d;
        h0buf[base * DS + n] = h;
        const float S = Sbuf[base];
        const float q = qbuf[base * DS + n];
        h = fmaf(h, __expf(Adn * S), q);
    }
}

__global__ __launch_bounds__(256) void scan_pass2(
    const float* __restrict__ dt, const float* __restrict__ xc,
    const float* __restrict__ xdbl, const float* __restrict__ xz,
    const float* __restrict__ Alog, const float* __restrict__ Dsk,
    const float* __restrict__ h0buf,
    ushort* __restrict__ yh, ushort* __restrict__ yl)   // hi/lo bf16 out
{
    __shared__ float sB[CH][16];
    __shared__ float sC[CH][16];
    const int b   = blockIdx.x;
    const int c   = blockIdx.y;
    const int d   = blockIdx.z * 256 + threadIdx.x;
    const int tid = threadIdx.x;

#pragma unroll
    for (int qq = 0; qq < 4; ++qq) {
        const int idx  = qq * 256 + tid;
        const int toff = idx >> 4;
        const int col  = idx & 15;
        const size_t row = (size_t)b * L_ + c * CH + toff;
        sB[toff][col] = xdbl[row * 48 + DTR + col];
        sC[toff][col] = xdbl[row * 48 + DTR + DS + col];
    }

    float Ad[16];
#pragma unroll
    for (int n = 0; n < 16; ++n) Ad[n] = -__expf(Alog[d * DS + n]);
    const float dskd = Dsk[d];

    float h[16];
    const float* h0 = h0buf + ((size_t)(c * B_ + b) * DI + d) * DS;
#pragma unroll
    for (int n4 = 0; n4 < 4; ++n4) {
        const float4 v = reinterpret_cast<const float4*>(h0)[n4];
        h[n4*4+0] = v.x; h[n4*4+1] = v.y; h[n4*4+2] = v.z; h[n4*4+3] = v.w;
    }

    __syncthreads();

    const size_t row0 = (size_t)b * L_ + c * CH;
    for (int tt = 0; tt < CH; ++tt) {
        const size_t row = row0 + tt;
        const float dtv = dt[row * DI + d];
        const float xv  = xc[row * DI + d];
        const float zv  = xz[row * (2*DI) + DI + d];
        const float u   = dtv * xv;

        const float4* Bt = reinterpret_cast<const float4*>(&sB[tt][0]);
        const float4* Ct = reinterpret_cast<const float4*>(&sC[tt][0]);
        const float4 b0 = Bt[0], b1 = Bt[1], b2 = Bt[2], b3 = Bt[3];
        const float4 c0 = Ct[0], c1 = Ct[1], c2 = Ct[2], c3 = Ct[3];
        const float bv[16] = {b0.x,b0.y,b0.z,b0.w, b1.x,b1.y,b1.z,b1.w,
                              b2.x,b2.y,b2.z,b2.w, b3.x,b3.y,b3.z,b3.w};
        const float cv[16] = {c0.x,c0.y,c0.z,c0.w, c1.x,c1.y,c1.z,c1.w,
                              c2.x,c2.y,c2.z,c2.w, c3.x,c3.y,c3.z,c3.w};

        float y0 = 0.f, y1 = 0.f, y2 = 0.f, y3 = 0.f;
#pragma unroll
        for (int n = 0; n < 4; ++n) {
            const float a0 = __expf(dtv * Ad[n]);
            const float a1 = __expf(dtv * Ad[n+4]);
            const float a2 = __expf(dtv * Ad[n+8]);
            const float a3 = __expf(dtv * Ad[n+12]);
            h[n]    = fmaf(h[n],    a0, u * bv[n]);
            h[n+4]  = fmaf(h[n+4],  a1, u * bv[n+4]);
            h[n+8]  = fmaf(h[n+8],  a2, u * bv[n+8]);
            h[n+12] = fmaf(h[n+12], a3, u * bv[n+12]);
            y0 = fmaf(h[n],    cv[n],    y0);
            y1 = fmaf(h[n+4],  cv[n+4],  y1);
            y2 = fmaf(h[n+8],  cv[n+8],  y2);
            y3 = fmaf(h[n+12], cv[n+12], y3);
        }
        const float y = (y0 + y1) + (y2 + y3);
        const float sz_ = zv / (1.f + __expf(-zv));
        const float yv  = (y + xv * dskd) * sz_;
        const ushort hb = f2bf(yv);
        yh[row * DI + d] = hb;
        yl[row * DI + d] = f2bf(yv - bf2f(hb));
    }
}

// ---------------------------------------------------------------------------
__global__ __launch_bounds__(256) void maskmean_kernel(
    const float* __restrict__ mask, float* __restrict__ m)
{
    const int row = blockIdx.x * 256 + threadIdx.x;
    const float* p = mask + (size_t)row * INPUT_;
    float s = 0.f;
#pragma unroll
    for (int k = 0; k < INPUT_; ++k) s += p[k];
    m[row] = s * (1.f / INPUT_);
}

__global__ __launch_bounds__(256) void pool_partial(
    const float* __restrict__ h, const float* __restrict__ m,
    float* __restrict__ partial, float* __restrict__ msum)
{
    const int b  = blockIdx.x;
    const int ch = blockIdx.y;
    const int c  = threadIdx.x;
    float acc = 0.f, ms = 0.f;
    const int l0 = ch * (L_ / PCH);
    for (int l = l0; l < l0 + (L_ / PCH); ++l) {
        const float mv = m[b * L_ + l];
        acc = fmaf(h[((size_t)b * L_ + l) * DM + c], mv, acc);
        ms += mv;
    }
    partial[((size_t)b * PCH + ch) * DM + c] = acc;
    if (c == 0) msum[b * PCH + ch] = ms;
}

__global__ __launch_bounds__(256) void pool_final(
    const float* __restrict__ partial, const float* __restrict__ msum,
    float* __restrict__ pooled)
{
    const int b = blockIdx.x;
    const int c = threadIdx.x;
    float acc = 0.f, ms = 0.f;
#pragma unroll
    for (int ch = 0; ch < PCH; ++ch) {
        acc += partial[((size_t)b * PCH + ch) * DM + c];
        ms  += msum[b * PCH + ch];
    }
    pooled[b * DM + c] = acc / (ms + 1e-8f);
}

__global__ __launch_bounds__(128) void head_kernel(
    const float* __restrict__ pooled,
    const float* __restrict__ fc1w, const float* __restrict__ fc1b,
    const float* __restrict__ fc2w, const float* __restrict__ fc2b,
    float* __restrict__ out)
{
    __shared__ float sp[DM];
    __shared__ float sh[128];
    const int b = blockIdx.x;
    const int j = threadIdx.x;
    sp[j]       = pooled[b * DM + j];
    sp[j + 128] = pooled[b * DM + j + 128];
    __syncthreads();
    float acc = fc1b[j];
    for (int k = 0; k < DM; ++k) acc = fmaf(sp[k], fc1w[j * DM + k], acc);
    const float g = 0.5f * acc * (1.f + erff(acc * 0.70710678118654752f));
    sh[j] = g * fc2w[j];
    __syncthreads();
    for (int s = 64; s > 0; s >>= 1) {
        if (j < s) sh[j] += sh[j + s];
        __syncthreads();
    }
    if (j == 0) out[b] = sh[0] + fc2b[0];
}

// ---------------------------------------------------------------------------
extern "C" void kernel_launch(void* const* d_in, const int* in_sizes, int n_in,
                              void* d_out, int out_size, void* d_ws, size_t ws_size,
                              hipStream_t stream)
{
    const float* x       = (const float*)d_in[0];
    const float* mask    = (const float*)d_in[1];
    const float* ipw     = (const float*)d_in[2];
    const float* ipb     = (const float*)d_in[3];
    const float* in_w    = (const float*)d_in[4];
    const float* conv_w  = (const float*)d_in[5];
    const float* conv_b  = (const float*)d_in[6];
    const float* xpw     = (const float*)d_in[7];
    const float* dtw     = (const float*)d_in[8];
    const float* dtb     = (const float*)d_in[9];
    const float* A_log   = (const float*)d_in[10];
    const float* D_skip  = (const float*)d_in[11];
    const float* out_w   = (const float*)d_in[12];
    const float* ln_g    = (const float*)d_in[13];
    const float* ln_b    = (const float*)d_in[14];
    const float* fc1w    = (const float*)d_in[15];
    const float* fc1b    = (const float*)d_in[16];
    const float* fc2w    = (const float*)d_in[17];
    const float* fc2b    = (const float*)d_in[18];
    float* outp = (float*)d_out;

    char* ws = (char*)d_ws;
    size_t off = 0;
    auto alloc = [&](size_t nfloats) {
        float* p = (float*)(ws + off);
        off += ((nfloats * 4 + 255) / 256) * 256;
        return p;
    };
    float*  hbuf    = alloc((size_t)BL * DM);
    float*  xzbuf   = alloc((size_t)BL * 2 * DI);
    float*  xcbuf   = alloc((size_t)BL * DI);
    float*  xdbl    = alloc((size_t)BL * 48);
    float*  dtbuf   = alloc((size_t)BL * DI);
    float*  mbuf    = alloc((size_t)BL);
    float*  pooled  = alloc((size_t)B_ * DM);
    float*  qbuf    = alloc((size_t)NC * B_ * DI * DS);
    float*  Sbuf    = alloc((size_t)NC * B_ * DI);
    float*  h0buf   = alloc((size_t)NC * B_ * DI * DS);
    float*  partial = alloc((size_t)B_ * PCH * DM);
    float*  msum    = alloc((size_t)B_ * PCH);
    // bf16 hi/lo buffers (ushort; alloc() counts floats -> halve)
    ushort* xlnh  = (ushort*)alloc((size_t)BL * DM / 2);
    ushort* xlnl  = (ushort*)alloc((size_t)BL * DM / 2);
    ushort* ych   = (ushort*)alloc((size_t)BL * DI / 2);
    ushort* ycl   = (ushort*)alloc((size_t)BL * DI / 2);
    ushort* inwh  = (ushort*)alloc((size_t)NL * 2 * DI * DM / 2);
    ushort* inwl  = (ushort*)alloc((size_t)NL * 2 * DI * DM / 2);
    ushort* owh   = (ushort*)alloc((size_t)NL * DM * DI / 2);
    ushort* owl   = (ushort*)alloc((size_t)NL * DM * DI / 2);
    (void)ws_size; (void)n_in; (void)in_sizes; (void)out_size;

    const dim3 blk(256);

    // one-time weight splits (graph-friendly: deterministic, every call)
    cvt_split<<<(NL*2*DI*DM/4 + 255)/256, blk, 0, stream>>>(in_w, inwh, inwl, NL*2*DI*DM/4);
    cvt_split<<<(NL*DM*DI/4   + 255)/256, blk, 0, stream>>>(out_w, owh, owl, NL*DM*DI/4);

    // input projection: h = x @ ipw.T + ipb   (f32, K=40)
    gemm_nt_64<<<dim3(BL/SBM, DM/SBN), blk, 0, stream>>>(
        x, INPUT_, ipw, INPUT_, ipb, nullptr, hbuf, DM, DM, INPUT_, 0);

    for (int i = 0; i < NL; ++i) {
        const float* cwi    = conv_w + (size_t)i * DI * DC;
        const float* cbi    = conv_b + (size_t)i * DI;
        const float* xpwi   = xpw    + (size_t)i * 48 * DI;
        const float* dtwi   = dtw    + (size_t)i * DI * DTR;
        const float* dtbi   = dtb    + (size_t)i * DI;
        const float* Alogi  = A_log  + (size_t)i * DI * DS;
        const float* Dski   = D_skip + (size_t)i * DI;
        const float* lngi   = ln_g   + (size_t)i * DM;
        const float* lnbi   = ln_b   + (size_t)i * DM;
        const ushort* inwhi = inwh + (size_t)i * 2 * DI * DM;
        const ushort* inwli = inwl + (size_t)i * 2 * DI * DM;
        const ushort* owhi  = owh  + (size_t)i * DM * DI;
        const ushort* owli  = owl  + (size_t)i * DM * DI;

        ln_kernel<<<BL, 64, 0, stream>>>(hbuf, lngi, lnbi, xlnh, xlnl);

        // xz = xln @ in_w.T  (MFMA bf16x3; M=16384, N=1024, K=256)
        gemm_mfma<<<dim3(BL/128, (2*DI)/128), blk, 0, stream>>>(
            xlnh, xlnl, inwhi, inwli, nullptr, xzbuf, 2*DI, DM);

        conv_silu<<<(BL * DI) / 256, blk, 0, stream>>>(xzbuf, cwi, cbi, xcbuf);

        // x_dbl = xc @ xpw.T  (f32; N=48, K=512)
        gemm_nt_64<<<dim3(BL/SBM, 1), blk, 0, stream>>>(
            xcbuf, DI, xpwi, DI, nullptr, nullptr, xdbl, 48, 48, DI, 0);

        // dt = softplus(x_dbl[:, :16] @ dtw.T + dtb)  (f32; N=512, K=16)
        gemm_nt_64<<<dim3(BL/SBM, DI/SBN), blk, 0, stream>>>(
            xdbl, 48, dtwi, DTR, dtbi, nullptr, dtbuf, DI, DI, DTR, 1);

        // selective scan -> ycomb (hi/lo bf16)
        scan_pass1<<<dim3(B_, NC, DI/256), blk, 0, stream>>>(
            dtbuf, xcbuf, xdbl, Alogi, qbuf, Sbuf);
        scan_compose<<<(B_ * DI * DS) / 256, blk, 0, stream>>>(
            qbuf, Sbuf, Alogi, h0buf);
        scan_pass2<<<dim3(B_, NC, DI/256), blk, 0, stream>>>(
            dtbuf, xcbuf, xdbl, xzbuf, Alogi, Dski, h0buf, ych, ycl);

        // h += ycomb @ ow.T  (MFMA bf16x3; N=256, K=512, residual)
        gemm_mfma<<<dim3(BL/128, DM/128), blk, 0, stream>>>(
            ych, ycl, owhi, owli, hbuf, hbuf, DM, DI);
    }

    maskmean_kernel<<<BL / 256, blk, 0, stream>>>(mask, mbuf);
    pool_partial<<<dim3(B_, PCH), blk, 0, stream>>>(hbuf, mbuf, partial, msum);
    pool_final<<<B_, blk, 0, stream>>>(partial, msum, pooled);
    head_kernel<<<B_, dim3(128), 0, stream>>>(pooled, fc1w, fc1b, fc2w, fc2b, outp);
}

// Round 5
// 1079.381 us; speedup vs baseline: 2.3254x; 1.0751x over previous
//
#include <hip/hip_runtime.h>
#include <math.h>

#define B_  16
#define L_  1024
#define INPUT_ 40
#define DM  256
#define DS  16
#define NL  4
#define DC  4
#define DI  512
#define DTR 16
#define BL  (B_ * L_)   // 16384
#define NC  32          // scan chunks
#define CH  32          // timesteps per chunk (NC*CH == L_)
#define PCH 16          // pool chunks over L

using bf16x8 = __attribute__((ext_vector_type(8))) short;
using f32x4  = __attribute__((ext_vector_type(4))) float;

__device__ __forceinline__ ushort f2bf(float x) {
    unsigned u = __float_as_uint(x);
    u += 0x7FFFu + ((u >> 16) & 1u);          // round-to-nearest-even
    return (ushort)(u >> 16);
}
__device__ __forceinline__ float bf2f(ushort h) {
    return __uint_as_float((unsigned)h << 16);
}

__device__ __forceinline__ void gload_lds16(const void* g, void* l) {
    __builtin_amdgcn_global_load_lds(
        (const __attribute__((address_space(1))) unsigned int*)g,
        (__attribute__((address_space(3))) unsigned int*)l, 16, 0, 0);
}

// ---------------------------------------------------------------------------
// split f32 -> (hi, lo) bf16 arrays, 4 elems/thread
// ---------------------------------------------------------------------------
__global__ __launch_bounds__(256) void cvt_split(
    const float* __restrict__ in, ushort* __restrict__ oh,
    ushort* __restrict__ ol, int n4)
{
    const int i = blockIdx.x * 256 + threadIdx.x;
    if (i >= n4) return;
    const float4 v = reinterpret_cast<const float4*>(in)[i];
    ushort4 h, l;
    h.x = f2bf(v.x); l.x = f2bf(v.x - bf2f(h.x));
    h.y = f2bf(v.y); l.y = f2bf(v.y - bf2f(h.y));
    h.z = f2bf(v.z); l.z = f2bf(v.z - bf2f(h.z));
    h.w = f2bf(v.w); l.w = f2bf(v.w - bf2f(h.w));
    reinterpret_cast<ushort4*>(oh)[i] = h;
    reinterpret_cast<ushort4*>(ol)[i] = l;
}

// ---------------------------------------------------------------------------
// MFMA bf16x3 GEMM: C[m][n] = sum_k A[m][k]*W[n][k] (+ Cin), A,W as hi/lo bf16.
// 128x128 tile, BK=32, 256 threads = 4 waves (2x2 of 64x64).
// Staging: direct global->LDS (global_load_lds, 16B), wave w owns matrix w.
// LDS slot-XOR swizzle via pre-swizzled GLOBAL source; LDS written linearly.
// m97 2-barrier structure: issue; bar (vmcnt drain); ds_read+MFMA; bar.
// ---------------------------------------------------------------------------
__global__ __launch_bounds__(256) void gemm_mfma(
    const ushort* __restrict__ Ah, const ushort* __restrict__ Al,
    const ushort* __restrict__ Wh, const ushort* __restrict__ Wl,
    const float* __restrict__ Cin, float* __restrict__ C,
    int ldc, int K)
{
    __shared__ ushort smem[4][128][32];   // [Ah, Al, Wh, Wl][row][k]

    const int tid  = threadIdx.x;
    const int m0   = blockIdx.x * 128;
    const int n0   = blockIdx.y * 128;
    const int lane = tid & 63;
    const int wv   = tid >> 6;
    const int wm   = wv >> 1, wn = wv & 1;

    // ---- staging source map: lane -> (row within 16-row group, swizzled slot)
    const int lrow = lane >> 2;                       // 0..15
    const int lswz = ((lane & 3) ^ (lrow & 3)) * 8;   // pre-swizzled k-slot (elems)
    const ushort* gbase;
    if      (wv == 0) gbase = Ah + (size_t)(m0 + lrow) * K + lswz;
    else if (wv == 1) gbase = Al + (size_t)(m0 + lrow) * K + lswz;
    else if (wv == 2) gbase = Wh + (size_t)(n0 + lrow) * K + lswz;
    else              gbase = Wl + (size_t)(n0 + lrow) * K + lswz;

    // ---- compute-read LDS pointers (constant across k-steps) ----
    const int ks = lane >> 4;      // k-slot 0..3 (8 bf16 each)
    const int lr = lane & 15;      // fragment row/col
    const ushort* rA[2][4];
    const ushort* rB[2][4];
#pragma unroll
    for (int f = 0; f < 4; ++f) {
        const int ar = wm * 64 + f * 16 + lr;
        const int as = (ks ^ (ar & 3)) * 8;
        rA[0][f] = &smem[0][ar][as];
        rA[1][f] = &smem[1][ar][as];
        const int bc = wn * 64 + f * 16 + lr;
        const int bs = (ks ^ (bc & 3)) * 8;
        rB[0][f] = &smem[2][bc][bs];
        rB[1][f] = &smem[3][bc][bs];
    }

    f32x4 acc[4][4];
#pragma unroll
    for (int i = 0; i < 4; ++i)
#pragma unroll
        for (int j = 0; j < 4; ++j)
            acc[i][j] = (f32x4){0.f, 0.f, 0.f, 0.f};

    for (int k0 = 0; k0 < K; k0 += 32) {
        // issue 8 direct-to-LDS loads (1 KiB each): rows 16i..16i+15 of my matrix
#pragma unroll
        for (int i = 0; i < 8; ++i)
            gload_lds16(gbase + (size_t)i * 16 * K + k0, &smem[wv][i * 16][0]);
        __syncthreads();   // vmcnt drain: tile resident

        bf16x8 ah[4], al[4], bh[4], bl[4];
#pragma unroll
        for (int f = 0; f < 4; ++f) {
            ah[f] = *reinterpret_cast<const bf16x8*>(rA[0][f]);
            al[f] = *reinterpret_cast<const bf16x8*>(rA[1][f]);
            bh[f] = *reinterpret_cast<const bf16x8*>(rB[0][f]);
            bl[f] = *reinterpret_cast<const bf16x8*>(rB[1][f]);
        }
#pragma unroll
        for (int mi = 0; mi < 4; ++mi)
#pragma unroll
            for (int ni = 0; ni < 4; ++ni) {
                acc[mi][ni] = __builtin_amdgcn_mfma_f32_16x16x32_bf16(al[mi], bh[ni], acc[mi][ni], 0, 0, 0);
                acc[mi][ni] = __builtin_amdgcn_mfma_f32_16x16x32_bf16(ah[mi], bl[ni], acc[mi][ni], 0, 0, 0);
                acc[mi][ni] = __builtin_amdgcn_mfma_f32_16x16x32_bf16(ah[mi], bh[ni], acc[mi][ni], 0, 0, 0);
            }
        __syncthreads();   // all reads done before next fill
    }

    // epilogue: C/D layout col=lane&15, row=(lane>>4)*4+reg
#pragma unroll
    for (int mi = 0; mi < 4; ++mi) {
        const int gr0 = m0 + wm * 64 + mi * 16 + ks * 4;
#pragma unroll
        for (int ni = 0; ni < 4; ++ni) {
            const int gc = n0 + wn * 64 + ni * 16 + lr;
#pragma unroll
            for (int rg = 0; rg < 4; ++rg) {
                float v = acc[mi][ni][rg];
                const size_t idx = (size_t)(gr0 + rg) * ldc + gc;
                if (Cin) v += Cin[idx];
                C[idx] = v;
            }
        }
    }
}

// ---------------------------------------------------------------------------
// Tiled f32 GEMM (small shapes): 64x64x16, 4x4/thread.
// ---------------------------------------------------------------------------
#define SBM 64
#define SBN 64
#define SBK 16

__global__ __launch_bounds__(256) void gemm_nt_64(
    const float* __restrict__ A, int lda,
    const float* __restrict__ W, int ldw,
    const float* __restrict__ bias,
    const float* __restrict__ Cin,
    float* __restrict__ C, int ldc,
    int N, int K, int act)
{
    __shared__ float As[SBK][SBM];
    __shared__ float Ws[SBK][SBN];

    const int tid = threadIdx.x;
    const int m0 = blockIdx.x * SBM;
    const int n0 = blockIdx.y * SBN;
    const int tx = tid & 15;
    const int ty = tid >> 4;
    const int r  = tid >> 2;
    const int kq = (tid & 3) * 4;

    float acc[4][4];
#pragma unroll
    for (int i = 0; i < 4; ++i)
#pragma unroll
        for (int j = 0; j < 4; ++j) acc[i][j] = 0.f;

    for (int k0 = 0; k0 < K; k0 += SBK) {
        {
            const int row = m0 + r;
            if (k0 + kq + 3 < K) {
                const float4 v = *reinterpret_cast<const float4*>(&A[(size_t)row * lda + k0 + kq]);
                As[kq+0][r] = v.x; As[kq+1][r] = v.y; As[kq+2][r] = v.z; As[kq+3][r] = v.w;
            } else {
#pragma unroll
                for (int i = 0; i < 4; ++i)
                    As[kq+i][r] = (k0 + kq + i < K) ? A[(size_t)row * lda + k0 + kq + i] : 0.f;
            }
        }
        {
            const int row = n0 + r;
            if (row < N && k0 + kq + 3 < K) {
                const float4 v = *reinterpret_cast<const float4*>(&W[(size_t)row * ldw + k0 + kq]);
                Ws[kq+0][r] = v.x; Ws[kq+1][r] = v.y; Ws[kq+2][r] = v.z; Ws[kq+3][r] = v.w;
            } else {
#pragma unroll
                for (int i = 0; i < 4; ++i)
                    Ws[kq+i][r] = (row < N && k0 + kq + i < K) ? W[(size_t)row * ldw + k0 + kq + i] : 0.f;
            }
        }
        __syncthreads();

#pragma unroll
        for (int k = 0; k < SBK; ++k) {
            const float4 a = *reinterpret_cast<const float4*>(&As[k][ty * 4]);
            const float4 b = *reinterpret_cast<const float4*>(&Ws[k][tx * 4]);
            const float av[4] = {a.x, a.y, a.z, a.w};
            const float bv[4] = {b.x, b.y, b.z, b.w};
#pragma unroll
            for (int i = 0; i < 4; ++i)
#pragma unroll
                for (int j = 0; j < 4; ++j)
                    acc[i][j] = fmaf(av[i], bv[j], acc[i][j]);
        }
        __syncthreads();
    }

#pragma unroll
    for (int i = 0; i < 4; ++i) {
        const int row = m0 + ty * 4 + i;
#pragma unroll
        for (int j = 0; j < 4; ++j) {
            const int col = n0 + tx * 4 + j;
            if (col < N) {
                float v = acc[i][j];
                if (bias) v += bias[col];
                if (act == 1) v = (v > 20.f) ? v : log1pf(expf(v));
                if (Cin) v += Cin[(size_t)row * ldc + col];
                C[(size_t)row * ldc + col] = v;
            }
        }
    }
}

// ---------------------------------------------------------------------------
// LayerNorm: one wave per row of 256; emits hi/lo bf16 for the MFMA GEMM.
// ---------------------------------------------------------------------------
__global__ __launch_bounds__(64) void ln_kernel(
    const float* __restrict__ h, const float* __restrict__ g,
    const float* __restrict__ bb,
    ushort* __restrict__ oh, ushort* __restrict__ ol)
{
    const int row = blockIdx.x;
    const int lane = threadIdx.x;
    const float4 v = *reinterpret_cast<const float4*>(&h[(size_t)row * DM + lane * 4]);
    float s  = v.x + v.y + v.z + v.w;
    float s2 = v.x*v.x + v.y*v.y + v.z*v.z + v.w*v.w;
#pragma unroll
    for (int m = 1; m < 64; m <<= 1) {
        s  += __shfl_xor(s, m);
        s2 += __shfl_xor(s2, m);
    }
    const float mu  = s * (1.f / DM);
    const float var = s2 * (1.f / DM) - mu * mu;
    const float rs  = rsqrtf(var + 1e-5f);
    const float4 gv = *reinterpret_cast<const float4*>(&g[lane * 4]);
    const float4 bv = *reinterpret_cast<const float4*>(&bb[lane * 4]);
    float o0 = (v.x - mu) * rs * gv.x + bv.x;
    float o1 = (v.y - mu) * rs * gv.y + bv.y;
    float o2 = (v.z - mu) * rs * gv.z + bv.z;
    float o3 = (v.w - mu) * rs * gv.w + bv.w;
    ushort4 hv, lv;
    hv.x = f2bf(o0); lv.x = f2bf(o0 - bf2f(hv.x));
    hv.y = f2bf(o1); lv.y = f2bf(o1 - bf2f(hv.y));
    hv.z = f2bf(o2); lv.z = f2bf(o2 - bf2f(hv.z));
    hv.w = f2bf(o3); lv.w = f2bf(o3 - bf2f(hv.w));
    *reinterpret_cast<ushort4*>(&oh[(size_t)row * DM + lane * 4]) = hv;
    *reinterpret_cast<ushort4*>(&ol[(size_t)row * DM + lane * 4]) = lv;
}

// ---------------------------------------------------------------------------
// Causal depthwise conv (k=4) + bias + SiLU; 4 consecutive t per thread.
// ---------------------------------------------------------------------------
__global__ __launch_bounds__(256) void conv_silu(
    const float* __restrict__ xz, const float* __restrict__ cw,
    const float* __restrict__ cb, float* __restrict__ xc)
{
    const int idx  = blockIdx.x * 256 + threadIdx.x;   // (BL/4)*DI total
    const int d    = idx & (DI - 1);
    const int rq   = idx >> 9;                          // 0..BL/4-1
    const int row0 = rq * 4;
    const int t0   = row0 & (L_ - 1);
    const float w0 = cw[d*4+0], w1 = cw[d*4+1], w2 = cw[d*4+2], w3 = cw[d*4+3];
    const float cbd = cb[d];
    const float* base = xz + (size_t)row0 * (2*DI) + d;

    float vm3 = 0.f, vm2 = 0.f, vm1 = 0.f;
    if (t0 != 0) {
        vm3 = base[-3 * (2*DI)];
        vm2 = base[-2 * (2*DI)];
        vm1 = base[-1 * (2*DI)];
    }
    const float c0 = base[0];
    const float c1 = base[1 * (2*DI)];
    const float c2 = base[2 * (2*DI)];
    const float c3 = base[3 * (2*DI)];

    // same fma order as before: cb + w3*cur, then +w2, +w1, +w0
    float a0 = cbd + w3 * c0;
    a0 = fmaf(w2, vm1, a0); a0 = fmaf(w1, vm2, a0); a0 = fmaf(w0, vm3, a0);
    float a1 = cbd + w3 * c1;
    a1 = fmaf(w2, c0, a1);  a1 = fmaf(w1, vm1, a1); a1 = fmaf(w0, vm2, a1);
    float a2 = cbd + w3 * c2;
    a2 = fmaf(w2, c1, a2);  a2 = fmaf(w1, c0, a2);  a2 = fmaf(w0, vm1, a2);
    float a3 = cbd + w3 * c3;
    a3 = fmaf(w2, c2, a3);  a3 = fmaf(w1, c1, a3);  a3 = fmaf(w0, c0, a3);

    xc[(size_t)(row0+0) * DI + d] = a0 / (1.f + __expf(-a0));
    xc[(size_t)(row0+1) * DI + d] = a1 / (1.f + __expf(-a1));
    xc[(size_t)(row0+2) * DI + d] = a2 / (1.f + __expf(-a2));
    xc[(size_t)(row0+3) * DI + d] = a3 / (1.f + __expf(-a3));
}

// ---------------------------------------------------------------------------
// Selective scan, chunk-parallel, n-in-registers.
// ---------------------------------------------------------------------------
__global__ __launch_bounds__(256) void scan_pass1(
    const float* __restrict__ dt, const float* __restrict__ xc,
    const float* __restrict__ xdbl, const float* __restrict__ Alog,
    float* __restrict__ qbuf, float* __restrict__ Sbuf)
{
    __shared__ float sB[CH][16];
    const int b   = blockIdx.x;
    const int c   = blockIdx.y;
    const int d   = blockIdx.z * 256 + threadIdx.x;
    const int tid = threadIdx.x;

#pragma unroll
    for (int qq = 0; qq < (CH * 16) / 256; ++qq) {
        const int idx  = qq * 256 + tid;
        const int toff = idx >> 4;
        const int col  = idx & 15;
        sB[toff][col] = xdbl[((size_t)b * L_ + c * CH + toff) * 48 + DTR + col];
    }

    float Ad[16];
#pragma unroll
    for (int n = 0; n < 16; ++n) Ad[n] = -__expf(Alog[d * DS + n]);

    __syncthreads();

    float q[16];
#pragma unroll
    for (int n = 0; n < 16; ++n) q[n] = 0.f;
    float S = 0.f;

    const size_t row0 = (size_t)b * L_ + c * CH;
    for (int tt = 0; tt < CH; ++tt) {
        const float dtv = dt[(row0 + tt) * DI + d];
        const float xv  = xc[(row0 + tt) * DI + d];
        const float u   = dtv * xv;
        S += dtv;
        const float4* Bt = reinterpret_cast<const float4*>(&sB[tt][0]);
        const float4 b0 = Bt[0], b1 = Bt[1], b2 = Bt[2], b3 = Bt[3];
        const float bv[16] = {b0.x,b0.y,b0.z,b0.w, b1.x,b1.y,b1.z,b1.w,
                              b2.x,b2.y,b2.z,b2.w, b3.x,b3.y,b3.z,b3.w};
#pragma unroll
        for (int n = 0; n < 16; ++n) {
            const float a = __expf(dtv * Ad[n]);
            q[n] = fmaf(q[n], a, u * bv[n]);
        }
    }

    float* qb = qbuf + ((size_t)(c * B_ + b) * DI + d) * DS;
#pragma unroll
    for (int n4 = 0; n4 < 4; ++n4)
        reinterpret_cast<float4*>(qb)[n4] =
            make_float4(q[n4*4+0], q[n4*4+1], q[n4*4+2], q[n4*4+3]);
    Sbuf[(size_t)(c * B_ + b) * DI + d] = S;
}

__global__ __launch_bounds__(256) void scan_compose(
    const float* __restrict__ qbuf, const float* __restrict__ Sbuf,
    const float* __restrict__ Alog, float* __restrict__ h0buf)
{
    const int gid = blockIdx.x * 256 + threadIdx.x;
    const int n = gid & 15;
    const int d = (gid >> 4) & (DI - 1);
    const int b = gid >> 13;
    const float Adn = -__expf(Alog[d * DS + n]);
    float h = 0.f;
    for (int c = 0; c < NC; ++c) {
        const size_t base = (size_t)(c * B_ + b) * DI + d;
        h0buf[base * DS + n] = h;
        const float S = Sbuf[base];
        const float q = qbuf[base * DS + n];
        h = fmaf(h, __expf(Adn * S), q);
    }
}

__global__ __launch_bounds__(256) void scan_pass2(
    const float* __restrict__ dt, const float* __restrict__ xc,
    const float* __restrict__ xdbl, const float* __restrict__ xz,
    const float* __restrict__ Alog, const float* __restrict__ Dsk,
    const float* __restrict__ h0buf,
    ushort* __restrict__ yh, ushort* __restrict__ yl)   // hi/lo bf16 out
{
    __shared__ float sB[CH][16];
    __shared__ float sC[CH][16];
    const int b   = blockIdx.x;
    const int c   = blockIdx.y;
    const int d   = blockIdx.z * 256 + threadIdx.x;
    const int tid = threadIdx.x;

#pragma unroll
    for (int qq = 0; qq < (CH * 16) / 256; ++qq) {
        const int idx  = qq * 256 + tid;
        const int toff = idx >> 4;
        const int col  = idx & 15;
        const size_t row = (size_t)b * L_ + c * CH + toff;
        sB[toff][col] = xdbl[row * 48 + DTR + col];
        sC[toff][col] = xdbl[row * 48 + DTR + DS + col];
    }

    float Ad[16];
#pragma unroll
    for (int n = 0; n < 16; ++n) Ad[n] = -__expf(Alog[d * DS + n]);
    const float dskd = Dsk[d];

    float h[16];
    const float* h0 = h0buf + ((size_t)(c * B_ + b) * DI + d) * DS;
#pragma unroll
    for (int n4 = 0; n4 < 4; ++n4) {
        const float4 v = reinterpret_cast<const float4*>(h0)[n4];
        h[n4*4+0] = v.x; h[n4*4+1] = v.y; h[n4*4+2] = v.z; h[n4*4+3] = v.w;
    }

    __syncthreads();

    const size_t row0 = (size_t)b * L_ + c * CH;
    for (int tt = 0; tt < CH; ++tt) {
        const size_t row = row0 + tt;
        const float dtv = dt[row * DI + d];
        const float xv  = xc[row * DI + d];
        const float zv  = xz[row * (2*DI) + DI + d];
        const float u   = dtv * xv;

        const float4* Bt = reinterpret_cast<const float4*>(&sB[tt][0]);
        const float4* Ct = reinterpret_cast<const float4*>(&sC[tt][0]);
        const float4 b0 = Bt[0], b1 = Bt[1], b2 = Bt[2], b3 = Bt[3];
        const float4 c0 = Ct[0], c1 = Ct[1], c2 = Ct[2], c3 = Ct[3];
        const float bv[16] = {b0.x,b0.y,b0.z,b0.w, b1.x,b1.y,b1.z,b1.w,
                              b2.x,b2.y,b2.z,b2.w, b3.x,b3.y,b3.z,b3.w};
        const float cv[16] = {c0.x,c0.y,c0.z,c0.w, c1.x,c1.y,c1.z,c1.w,
                              c2.x,c2.y,c2.z,c2.w, c3.x,c3.y,c3.z,c3.w};

        float y0 = 0.f, y1 = 0.f, y2 = 0.f, y3 = 0.f;
#pragma unroll
        for (int n = 0; n < 4; ++n) {
            const float a0 = __expf(dtv * Ad[n]);
            const float a1 = __expf(dtv * Ad[n+4]);
            const float a2 = __expf(dtv * Ad[n+8]);
            const float a3 = __expf(dtv * Ad[n+12]);
            h[n]    = fmaf(h[n],    a0, u * bv[n]);
            h[n+4]  = fmaf(h[n+4],  a1, u * bv[n+4]);
            h[n+8]  = fmaf(h[n+8],  a2, u * bv[n+8]);
            h[n+12] = fmaf(h[n+12], a3, u * bv[n+12]);
            y0 = fmaf(h[n],    cv[n],    y0);
            y1 = fmaf(h[n+4],  cv[n+4],  y1);
            y2 = fmaf(h[n+8],  cv[n+8],  y2);
            y3 = fmaf(h[n+12], cv[n+12], y3);
        }
        const float y = (y0 + y1) + (y2 + y3);
        const float sz_ = zv / (1.f + __expf(-zv));
        const float yv  = (y + xv * dskd) * sz_;
        const ushort hb = f2bf(yv);
        yh[row * DI + d] = hb;
        yl[row * DI + d] = f2bf(yv - bf2f(hb));
    }
}

// ---------------------------------------------------------------------------
__global__ __launch_bounds__(256) void maskmean_kernel(
    const float* __restrict__ mask, float* __restrict__ m)
{
    const int row = blockIdx.x * 256 + threadIdx.x;
    const float* p = mask + (size_t)row * INPUT_;
    float s = 0.f;
#pragma unroll
    for (int k = 0; k < INPUT_; ++k) s += p[k];
    m[row] = s * (1.f / INPUT_);
}

__global__ __launch_bounds__(256) void pool_partial(
    const float* __restrict__ h, const float* __restrict__ m,
    float* __restrict__ partial, float* __restrict__ msum)
{
    const int b  = blockIdx.x;
    const int ch = blockIdx.y;
    const int c  = threadIdx.x;
    float acc = 0.f, ms = 0.f;
    const int l0 = ch * (L_ / PCH);
    for (int l = l0; l < l0 + (L_ / PCH); ++l) {
        const float mv = m[b * L_ + l];
        acc = fmaf(h[((size_t)b * L_ + l) * DM + c], mv, acc);
        ms += mv;
    }
    partial[((size_t)b * PCH + ch) * DM + c] = acc;
    if (c == 0) msum[b * PCH + ch] = ms;
}

__global__ __launch_bounds__(256) void pool_final(
    const float* __restrict__ partial, const float* __restrict__ msum,
    float* __restrict__ pooled)
{
    const int b = blockIdx.x;
    const int c = threadIdx.x;
    float acc = 0.f, ms = 0.f;
#pragma unroll
    for (int ch = 0; ch < PCH; ++ch) {
        acc += partial[((size_t)b * PCH + ch) * DM + c];
        ms  += msum[b * PCH + ch];
    }
    pooled[b * DM + c] = acc / (ms + 1e-8f);
}

__global__ __launch_bounds__(128) void head_kernel(
    const float* __restrict__ pooled,
    const float* __restrict__ fc1w, const float* __restrict__ fc1b,
    const float* __restrict__ fc2w, const float* __restrict__ fc2b,
    float* __restrict__ out)
{
    __shared__ float sp[DM];
    __shared__ float sh[128];
    const int b = blockIdx.x;
    const int j = threadIdx.x;
    sp[j]       = pooled[b * DM + j];
    sp[j + 128] = pooled[b * DM + j + 128];
    __syncthreads();
    float acc = fc1b[j];
    for (int k = 0; k < DM; ++k) acc = fmaf(sp[k], fc1w[j * DM + k], acc);
    const float g = 0.5f * acc * (1.f + erff(acc * 0.70710678118654752f));
    sh[j] = g * fc2w[j];
    __syncthreads();
    for (int s = 64; s > 0; s >>= 1) {
        if (j < s) sh[j] += sh[j + s];
        __syncthreads();
    }
    if (j == 0) out[b] = sh[0] + fc2b[0];
}

// ---------------------------------------------------------------------------
extern "C" void kernel_launch(void* const* d_in, const int* in_sizes, int n_in,
                              void* d_out, int out_size, void* d_ws, size_t ws_size,
                              hipStream_t stream)
{
    const float* x       = (const float*)d_in[0];
    const float* mask    = (const float*)d_in[1];
    const float* ipw     = (const float*)d_in[2];
    const float* ipb     = (const float*)d_in[3];
    const float* in_w    = (const float*)d_in[4];
    const float* conv_w  = (const float*)d_in[5];
    const float* conv_b  = (const float*)d_in[6];
    const float* xpw     = (const float*)d_in[7];
    const float* dtw     = (const float*)d_in[8];
    const float* dtb     = (const float*)d_in[9];
    const float* A_log   = (const float*)d_in[10];
    const float* D_skip  = (const float*)d_in[11];
    const float* out_w   = (const float*)d_in[12];
    const float* ln_g    = (const float*)d_in[13];
    const float* ln_b    = (const float*)d_in[14];
    const float* fc1w    = (const float*)d_in[15];
    const float* fc1b    = (const float*)d_in[16];
    const float* fc2w    = (const float*)d_in[17];
    const float* fc2b    = (const float*)d_in[18];
    float* outp = (float*)d_out;

    char* ws = (char*)d_ws;
    size_t off = 0;
    auto alloc = [&](size_t nfloats) {
        float* p = (float*)(ws + off);
        off += ((nfloats * 4 + 255) / 256) * 256;
        return p;
    };
    float*  hbuf    = alloc((size_t)BL * DM);
    float*  xzbuf   = alloc((size_t)BL * 2 * DI);
    float*  xcbuf   = alloc((size_t)BL * DI);
    float*  xdbl    = alloc((size_t)BL * 48);
    float*  dtbuf   = alloc((size_t)BL * DI);
    float*  mbuf    = alloc((size_t)BL);
    float*  pooled  = alloc((size_t)B_ * DM);
    float*  qbuf    = alloc((size_t)NC * B_ * DI * DS);
    float*  Sbuf    = alloc((size_t)NC * B_ * DI);
    float*  h0buf   = alloc((size_t)NC * B_ * DI * DS);
    float*  partial = alloc((size_t)B_ * PCH * DM);
    float*  msum    = alloc((size_t)B_ * PCH);
    // bf16 hi/lo buffers (ushort; alloc() counts floats -> halve)
    ushort* xlnh  = (ushort*)alloc((size_t)BL * DM / 2);
    ushort* xlnl  = (ushort*)alloc((size_t)BL * DM / 2);
    ushort* ych   = (ushort*)alloc((size_t)BL * DI / 2);
    ushort* ycl   = (ushort*)alloc((size_t)BL * DI / 2);
    ushort* inwh  = (ushort*)alloc((size_t)NL * 2 * DI * DM / 2);
    ushort* inwl  = (ushort*)alloc((size_t)NL * 2 * DI * DM / 2);
    ushort* owh   = (ushort*)alloc((size_t)NL * DM * DI / 2);
    ushort* owl   = (ushort*)alloc((size_t)NL * DM * DI / 2);
    (void)ws_size; (void)n_in; (void)in_sizes; (void)out_size;

    const dim3 blk(256);

    // one-time weight splits
    cvt_split<<<(NL*2*DI*DM/4 + 255)/256, blk, 0, stream>>>(in_w, inwh, inwl, NL*2*DI*DM/4);
    cvt_split<<<(NL*DM*DI/4   + 255)/256, blk, 0, stream>>>(out_w, owh, owl, NL*DM*DI/4);

    // input projection: h = x @ ipw.T + ipb   (f32, K=40)
    gemm_nt_64<<<dim3(BL/SBM, DM/SBN), blk, 0, stream>>>(
        x, INPUT_, ipw, INPUT_, ipb, nullptr, hbuf, DM, DM, INPUT_, 0);

    for (int i = 0; i < NL; ++i) {
        const float* cwi    = conv_w + (size_t)i * DI * DC;
        const float* cbi    = conv_b + (size_t)i * DI;
        const float* xpwi   = xpw    + (size_t)i * 48 * DI;
        const float* dtwi   = dtw    + (size_t)i * DI * DTR;
        const float* dtbi   = dtb    + (size_t)i * DI;
        const float* Alogi  = A_log  + (size_t)i * DI * DS;
        const float* Dski   = D_skip + (size_t)i * DI;
        const float* lngi   = ln_g   + (size_t)i * DM;
        const float* lnbi   = ln_b   + (size_t)i * DM;
        const ushort* inwhi = inwh + (size_t)i * 2 * DI * DM;
        const ushort* inwli = inwl + (size_t)i * 2 * DI * DM;
        const ushort* owhi  = owh  + (size_t)i * DM * DI;
        const ushort* owli  = owl  + (size_t)i * DM * DI;

        ln_kernel<<<BL, 64, 0, stream>>>(hbuf, lngi, lnbi, xlnh, xlnl);

        // xz = xln @ in_w.T  (MFMA bf16x3; M=16384, N=1024, K=256)
        gemm_mfma<<<dim3(BL/128, (2*DI)/128), blk, 0, stream>>>(
            xlnh, xlnl, inwhi, inwli, nullptr, xzbuf, 2*DI, DM);

        conv_silu<<<(BL/4 * DI) / 256, blk, 0, stream>>>(xzbuf, cwi, cbi, xcbuf);

        // x_dbl = xc @ xpw.T  (f32; N=48, K=512)
        gemm_nt_64<<<dim3(BL/SBM, 1), blk, 0, stream>>>(
            xcbuf, DI, xpwi, DI, nullptr, nullptr, xdbl, 48, 48, DI, 0);

        // dt = softplus(x_dbl[:, :16] @ dtw.T + dtb)  (f32; N=512, K=16)
        gemm_nt_64<<<dim3(BL/SBM, DI/SBN), blk, 0, stream>>>(
            xdbl, 48, dtwi, DTR, dtbi, nullptr, dtbuf, DI, DI, DTR, 1);

        // selective scan -> ycomb (hi/lo bf16)
        scan_pass1<<<dim3(B_, NC, DI/256), blk, 0, stream>>>(
            dtbuf, xcbuf, xdbl, Alogi, qbuf, Sbuf);
        scan_compose<<<(B_ * DI * DS) / 256, blk, 0, stream>>>(
            qbuf, Sbuf, Alogi, h0buf);
        scan_pass2<<<dim3(B_, NC, DI/256), blk, 0, stream>>>(
            dtbuf, xcbuf, xdbl, xzbuf, Alogi, Dski, h0buf, ych, ycl);

        // h += ycomb @ ow.T  (MFMA bf16x3; N=256, K=512, residual)
        gemm_mfma<<<dim3(BL/128, DM/128), blk, 0, stream>>>(
            ych, ycl, owhi, owli, hbuf, hbuf, DM, DI);
    }

    maskmean_kernel<<<BL / 256, blk, 0, stream>>>(mask, mbuf);
    pool_partial<<<dim3(B_, PCH), blk, 0, stream>>>(hbuf, mbuf, partial, msum);
    pool_final<<<B_, blk, 0, stream>>>(partial, msum, pooled);
    head_kernel<<<B_, dim3(128), 0, stream>>>(pooled, fc1w, fc1b, fc2w, fc2b, outp);
}